// Round 1
// baseline (1256.016 us; speedup 1.0000x reference)
//
#include <hip/hip_runtime.h>

#define H 128
#define RNUM 8
#define TNUM 2
#define PNUM 1000
#define MNUM 223

__device__ __forceinline__ float fsig(float z) {
    return 1.0f / (1.0f + __expf(-z));
}

__device__ __forceinline__ float wave_reduce(float v) {
#pragma unroll
    for (int off = 32; off > 0; off >>= 1) v += __shfl_down(v, off, 64);
    return v;
}

__device__ __forceinline__ float f4c(const float4& v, int q) {
    return q == 0 ? v.x : q == 1 ? v.y : q == 2 ? v.z : v.w;
}

// ---------------------------------------------------------------------------
// K1: collapse fc -> w_nt -> w_rel into C[t][r][c][o], c in {ntc0, ntc1, bias}
// C[((t*8+r)*3+c)*128+o]; rank-2 structure of h0 makes this exact.
// ---------------------------------------------------------------------------
__global__ void precompute_C(const float* __restrict__ fc_w, const float* __restrict__ fc_b,
                             const float* __restrict__ w_nt, const float* __restrict__ w_rel,
                             float* __restrict__ C) {
    __shared__ float G[2][2][H];   // G[t][c][i] = sum_j fc_w[c][j] * w_nt[t][j][i]
    __shared__ float g[2][H];      // g[t][i]    = sum_j fc_b[j]   * w_nt[t][j][i]
    int tid = threadIdx.x;
    for (int idx = tid; idx < 2 * 2 * H; idx += 256) {
        int t = idx >> 8, c = (idx >> 7) & 1, i = idx & 127;
        float s = 0.f;
        for (int j = 0; j < H; ++j) s += fc_w[c * H + j] * w_nt[((size_t)t * H + j) * H + i];
        G[t][c][i] = s;
    }
    for (int idx = tid; idx < 2 * H; idx += 256) {
        int t = idx >> 7, i = idx & 127;
        float s = 0.f;
        for (int j = 0; j < H; ++j) s += fc_b[j] * w_nt[((size_t)t * H + j) * H + i];
        g[t][i] = s;
    }
    __syncthreads();
    for (int idx = tid; idx < 6144; idx += 256) {
        int o = idx & 127;
        int c = (idx >> 7) % 3;
        int pair = idx / 384;           // t*8+r
        int r = pair & 7, t = pair >> 3;
        float s = 0.f;
        if (c == 2) {
            for (int i = 0; i < H; ++i) s += g[t][i] * w_rel[((size_t)r * H + i) * H + o];
        } else {
            for (int i = 0; i < H; ++i) s += G[t][c][i] * w_rel[((size_t)r * H + i) * H + o];
        }
        C[idx] = s;
    }
}

// ---------------------------------------------------------------------------
// K2: per-edge scatter of (norm*c0, norm*c1, norm) into S[dst][t*8+r][3]
// 3 atomics/edge instead of 128.
// ---------------------------------------------------------------------------
__global__ void edge_scatter(const int* __restrict__ src, const int* __restrict__ dst,
                             const int* __restrict__ etype, const float* __restrict__ norm,
                             const int* __restrict__ node_type, const float* __restrict__ ntc,
                             float* __restrict__ S, int E) {
    int e = blockIdx.x * 256 + threadIdx.x;
    if (e >= E) return;
    int s = src[e];
    int d = dst[e];
    int r = etype[e];
    float nm = norm[e];
    int t = node_type[s];
    float2 c = ((const float2*)ntc)[s];
    float* p = S + (size_t)d * 48 + (t * 8 + r) * 3;
    atomicAdd(p, nm * c.x);
    atomicAdd(p + 1, nm * c.y);
    atomicAdd(p + 2, nm);
}

// ---------------------------------------------------------------------------
// K3: h[v] = relu(S[v,0:48] @ C[48,128]); also pred[v]=clamp(sigmoid(h.fc2_w+b))
// and gsum += h (for mean_nodes). 32 nodes/block, 8 threads/node, 16 out/thread
// as 4 float4 groups o = q*32 + sub*4 (bank-conflict-free C reads).
// ---------------------------------------------------------------------------
__global__ void node_kernel(const float* __restrict__ S, const float* __restrict__ C,
                            const float* __restrict__ fc2_w, const float* __restrict__ fc2_b,
                            float* __restrict__ h, float* __restrict__ pred,
                            float* __restrict__ gsum, int N) {
    __shared__ float Csh[48 * 128];
    __shared__ float Ssh[32 * 49];   // pad 48->49 to spread banks
    __shared__ float gloc[128];
    int tid = threadIdx.x;
    for (int i = tid; i < 48 * 128; i += 256) Csh[i] = C[i];
    int base = blockIdx.x * 32;
    for (int i = tid; i < 32 * 48; i += 256) {
        int vl = i / 48, k = i - vl * 48;
        int v = base + vl;
        Ssh[vl * 49 + k] = (v < N) ? S[(size_t)v * 48 + k] : 0.0f;
    }
    if (tid < 128) gloc[tid] = 0.0f;
    __syncthreads();

    int sub = tid & 7, vl = tid >> 3;
    int v = base + vl;
    float4 hv[4];
#pragma unroll
    for (int q = 0; q < 4; ++q) hv[q] = make_float4(0.f, 0.f, 0.f, 0.f);
    const float* Srow = Ssh + vl * 49;
#pragma unroll 4
    for (int k = 0; k < 48; ++k) {
        float sv = Srow[k];
        const float4* Cr = (const float4*)(Csh + k * 128);
#pragma unroll
        for (int q = 0; q < 4; ++q) {
            float4 c = Cr[q * 8 + sub];
            hv[q].x += sv * c.x; hv[q].y += sv * c.y;
            hv[q].z += sv * c.z; hv[q].w += sv * c.w;
        }
    }
    // relu
#pragma unroll
    for (int q = 0; q < 4; ++q) {
        hv[q].x = fmaxf(hv[q].x, 0.f); hv[q].y = fmaxf(hv[q].y, 0.f);
        hv[q].z = fmaxf(hv[q].z, 0.f); hv[q].w = fmaxf(hv[q].w, 0.f);
    }
    float pd = 0.f;
    if (v < N) {
        float4* hrow = (float4*)(h + (size_t)v * H);
        const float4* w4 = (const float4*)fc2_w;
#pragma unroll
        for (int q = 0; q < 4; ++q) {
            hrow[q * 8 + sub] = hv[q];
            float4 w = w4[q * 8 + sub];
            pd += hv[q].x * w.x + hv[q].y * w.y + hv[q].z * w.z + hv[q].w * w.w;
        }
    }
    // pred: reduce pd over the 8 sub-threads of this node
#pragma unroll
    for (int off = 4; off > 0; off >>= 1) pd += __shfl_down(pd, off, 8);
    if (sub == 0 && v < N) {
        float z = pd + fc2_b[0];
        pred[v] = fminf(fmaxf(fsig(z), 1e-7f), 1e10f);
    }
    // gsum: wave-level pre-reduce over vl (lanes stride 8), then LDS, then global
#pragma unroll
    for (int q = 0; q < 4; ++q) {
        float4 x = (v < N) ? hv[q] : make_float4(0.f, 0.f, 0.f, 0.f);
#pragma unroll
        for (int d = 8; d < 64; d <<= 1) {
            x.x += __shfl_down(x.x, d, 64); x.y += __shfl_down(x.y, d, 64);
            x.z += __shfl_down(x.z, d, 64); x.w += __shfl_down(x.w, d, 64);
        }
        if ((tid & 63) < 8) {
            int o = q * 32 + sub * 4;
            atomicAdd(&gloc[o], x.x); atomicAdd(&gloc[o + 1], x.y);
            atomicAdd(&gloc[o + 2], x.z); atomicAdd(&gloc[o + 3], x.w);
        }
    }
    __syncthreads();
    if (tid < 128) atomicAdd(&gsum[tid], gloc[tid]);
}

// ---------------------------------------------------------------------------
// K4: prob3_sum = sum sigmoid(h[N,128] @ fl3_w[128,1000] + fl3_b)
// 128x128 tile, 8x8 micro, k staged in 32-chunks (LDS 34.8KB -> 4 blocks/CU).
// ---------------------------------------------------------------------------
#define FMA4(A, s, W) { (A).x += (s)*(W).x; (A).y += (s)*(W).y; (A).z += (s)*(W).z; (A).w += (s)*(W).w; }

__global__ __launch_bounds__(256) void prob3_kernel(const float* __restrict__ h,
                                                    const float* __restrict__ w,
                                                    const float* __restrict__ bias,
                                                    float* __restrict__ out, int N) {
    __shared__ float hsh[128 * 36];  // [i][k] pad 32->36 (bank spread, f4-aligned)
    __shared__ float wsh[32 * 128];  // [k][p]
    int tid = threadIdx.x;
    int bp = blockIdx.x & 7;
    int bn = blockIdx.x >> 3;
    int n0 = bn * 128, p0 = bp * 128;
    int tx = tid & 15, ty = tid >> 4;

    float4 acc[8][2];
#pragma unroll
    for (int ii = 0; ii < 8; ++ii) {
        acc[ii][0] = make_float4(0.f, 0.f, 0.f, 0.f);
        acc[ii][1] = make_float4(0.f, 0.f, 0.f, 0.f);
    }

    for (int st = 0; st < 4; ++st) {
        __syncthreads();
        // stage h: rows i=0..127, k = st*32 .. +31
        for (int l = tid; l < 1024; l += 256) {
            int i = l >> 3, kq = l & 7;
            int v = n0 + i;
            float4 val = make_float4(0.f, 0.f, 0.f, 0.f);
            if (v < N) val = *(const float4*)(h + (size_t)v * H + st * 32 + kq * 4);
            *(float4*)(hsh + i * 36 + kq * 4) = val;
        }
        // stage w: k rows st*32..+31, p = p0..p0+127
        for (int l = tid; l < 1024; l += 256) {
            int kl = l >> 5, pq = l & 31;
            int p = p0 + pq * 4;
            float4 val = make_float4(0.f, 0.f, 0.f, 0.f);
            if (p < PNUM) val = *(const float4*)(w + (size_t)(st * 32 + kl) * PNUM + p);
            *(float4*)(wsh + kl * 128 + pq * 4) = val;
        }
        __syncthreads();
#pragma unroll
        for (int ks = 0; ks < 32; ks += 4) {
            float4 wv[4][2];
#pragma unroll
            for (int kk = 0; kk < 4; ++kk) {
                wv[kk][0] = *(const float4*)(wsh + (ks + kk) * 128 + tx * 4);
                wv[kk][1] = *(const float4*)(wsh + (ks + kk) * 128 + 64 + tx * 4);
            }
#pragma unroll
            for (int ii = 0; ii < 8; ++ii) {
                float4 a = *(const float4*)(hsh + (ty + 16 * ii) * 36 + ks);
                FMA4(acc[ii][0], a.x, wv[0][0]); FMA4(acc[ii][1], a.x, wv[0][1]);
                FMA4(acc[ii][0], a.y, wv[1][0]); FMA4(acc[ii][1], a.y, wv[1][1]);
                FMA4(acc[ii][0], a.z, wv[2][0]); FMA4(acc[ii][1], a.z, wv[2][1]);
                FMA4(acc[ii][0], a.w, wv[3][0]); FMA4(acc[ii][1], a.w, wv[3][1]);
            }
        }
    }

    float lsum = 0.f;
#pragma unroll
    for (int ii = 0; ii < 8; ++ii) {
        int v = n0 + ty + 16 * ii;
        if (v < N) {
#pragma unroll
            for (int g = 0; g < 2; ++g) {
                int pb = p0 + g * 64 + tx * 4;
#pragma unroll
                for (int q = 0; q < 4; ++q) {
                    int p = pb + q;
                    if (p < PNUM) lsum += fsig(f4c(acc[ii][g], q) + bias[p]);
                }
            }
        }
    }
    lsum = wave_reduce(lsum);
    if ((tid & 63) == 0) atomicAdd(out + 5, lsum);
}

// ---------------------------------------------------------------------------
// K5: agg[dst] += pred[src]
// ---------------------------------------------------------------------------
__global__ void agg_edges(const int* __restrict__ src, const int* __restrict__ dst,
                          const float* __restrict__ pred, float* __restrict__ agg, int E) {
    int e = blockIdx.x * 256 + threadIdx.x;
    if (e >= E) return;
    atomicAdd(&agg[dst[e]], pred[src[e]]);
}

// K6: out_cost = sum (agg-1)^2 * special_cost
__global__ void outcost_kernel(const float* __restrict__ agg, const float* __restrict__ sc,
                               float* __restrict__ out, int N) {
    int i = blockIdx.x * 256 + threadIdx.x;
    float v = 0.f;
    if (i < N) { float d = agg[i] - 1.0f; v = d * d * sc[i]; }
    v = wave_reduce(v);
    if ((threadIdx.x & 63) == 0) atomicAdd(out + 4, v);
}

// K7: row sums rs[i], col sums cs[j] of pm = pred[:M*M]
__global__ void rowcol_kernel(const float* __restrict__ pred, float* __restrict__ rs,
                              float* __restrict__ cs) {
    int i = blockIdx.x;
    int j = threadIdx.x;
    float p = (j < MNUM) ? pred[i * MNUM + j] : 0.0f;
    if (j < MNUM) atomicAdd(&cs[j], p);
    float s = wave_reduce(p);
    if ((j & 63) == 0) atomicAdd(&rs[i], s);
}

// K8: ce and loss2
__global__ void losses_kernel(const float* __restrict__ pred, const float* __restrict__ gt,
                              const float* __restrict__ rs, const float* __restrict__ cs,
                              float* __restrict__ out) {
    int idx = blockIdx.x * 256 + threadIdx.x;
    float ce = 0.f, l2 = 0.f;
    if (idx < MNUM * MNUM) {
        int i = idx / MNUM, j = idx - i * MNUM;
        float p = pred[idx];
        ce = -gt[idx] * __log2f(p);
        l2 = p * (rs[i] + cs[j] - 2.0f * p);
    }
    ce = wave_reduce(ce);
    l2 = wave_reduce(l2);
    if ((threadIdx.x & 63) == 0) { atomicAdd(out + 3, ce); atomicAdd(out + 2, l2); }
}

// K9: sumone = sum (rs-1)^2 + (cs-1)^2
__global__ void sumone_kernel(const float* __restrict__ rs, const float* __restrict__ cs,
                              float* __restrict__ out) {
    int j = threadIdx.x;
    float v = 0.f;
    if (j < MNUM) {
        float a = rs[j] - 1.0f, b = cs[j] - 1.0f;
        v = a * a + b * b;
    }
    v = wave_reduce(v);
    if ((j & 63) == 0) atomicAdd(out + 1, v);
}

// K10: pred_obj = mean(h) @ fc3_w + fc3_b
__global__ void final_kernel(const float* __restrict__ gsum, const float* __restrict__ fc3_w,
                             const float* __restrict__ fc3_b, float* __restrict__ out, int N) {
    int t = threadIdx.x;  // 64 threads
    float invN = 1.0f / (float)N;
    float v = gsum[t] * invN * fc3_w[t] + gsum[t + 64] * invN * fc3_w[t + 64];
    v = wave_reduce(v);
    if (t == 0) out[0] = v + fc3_b[0];
}

extern "C" void kernel_launch(void* const* d_in, const int* in_sizes, int n_in,
                              void* d_out, int out_size, void* d_ws, size_t ws_size,
                              hipStream_t stream) {
    const float* ntc   = (const float*)d_in[0];
    const float* norm  = (const float*)d_in[1];
    const float* sc    = (const float*)d_in[2];
    const float* gt    = (const float*)d_in[3];
    const float* fc_w  = (const float*)d_in[4];
    const float* fc_b  = (const float*)d_in[5];
    const float* w_nt  = (const float*)d_in[6];
    const float* w_rel = (const float*)d_in[7];
    const float* fc2_w = (const float*)d_in[8];
    const float* fc2_b = (const float*)d_in[9];
    const float* fc3_w = (const float*)d_in[10];
    const float* fc3_b = (const float*)d_in[11];
    const float* fl3_w = (const float*)d_in[12];
    const float* fl3_b = (const float*)d_in[13];
    const int* node_type = (const int*)d_in[14];
    const int* src   = (const int*)d_in[15];
    const int* dst   = (const int*)d_in[16];
    const int* etype = (const int*)d_in[17];
    int N = in_sizes[2];
    int E = in_sizes[1];

    float* ws   = (float*)d_ws;
    float* C    = ws;                 // 6144
    float* gsum = ws + 6144;          // 128
    float* rs   = ws + 6272;          // 256 (223 used)
    float* cs   = ws + 6528;          // 256
    float* pred = ws + 6784;          // N
    float* agg  = pred + N;           // N
    float* S    = agg + N;            // N*48
    float* h    = S + (size_t)N * 48; // N*128
    float* out  = (float*)d_out;

    hipMemsetAsync(d_out, 0, 6 * sizeof(float), stream);
    // zero gsum, rs, cs, pred, agg, S (contiguous): 640 + 50*N floats
    hipMemsetAsync(gsum, 0, (size_t)(640 + 50 * (size_t)N) * sizeof(float), stream);

    precompute_C<<<1, 256, 0, stream>>>(fc_w, fc_b, w_nt, w_rel, C);
    edge_scatter<<<(E + 255) / 256, 256, 0, stream>>>(src, dst, etype, norm, node_type, ntc, S, E);
    node_kernel<<<(N + 31) / 32, 256, 0, stream>>>(S, C, fc2_w, fc2_b, h, pred, gsum, N);
    prob3_kernel<<<((N + 127) / 128) * 8, 256, 0, stream>>>(h, fl3_w, fl3_b, out, N);
    agg_edges<<<(E + 255) / 256, 256, 0, stream>>>(src, dst, pred, agg, E);
    outcost_kernel<<<(N + 255) / 256, 256, 0, stream>>>(agg, sc, out, N);
    rowcol_kernel<<<MNUM, 256, 0, stream>>>(pred, rs, cs);
    losses_kernel<<<(MNUM * MNUM + 255) / 256, 256, 0, stream>>>(pred, gt, rs, cs, out);
    sumone_kernel<<<1, 256, 0, stream>>>(rs, cs, out);
    final_kernel<<<1, 64, 0, stream>>>(gsum, fc3_w, fc3_b, out, N);
}

// Round 2
// 809.436 us; speedup vs baseline: 1.5517x; 1.5517x over previous
//
#include <hip/hip_runtime.h>

#define H 128
#define RNUM 8
#define TNUM 2
#define PNUM 1000
#define MNUM 223

__device__ __forceinline__ float fsig(float z) {
    return 1.0f / (1.0f + __expf(-z));
}

__device__ __forceinline__ float wave_reduce(float v) {
#pragma unroll
    for (int off = 32; off > 0; off >>= 1) v += __shfl_down(v, off, 64);
    return v;
}

__device__ __forceinline__ float f4c(const float4& v, int q) {
    return q == 0 ? v.x : q == 1 ? v.y : q == 2 ? v.z : v.w;
}

// ---------------------------------------------------------------------------
// K1a: G[t][c][i] = sum_j coef[c][j] * w_nt[t][j][i], coef rows = fc_w[0],
// fc_w[1], fc_b. Grid: 2 blocks (t), 128 threads (i). Coalesced w_nt reads.
// ---------------------------------------------------------------------------
__global__ void precompute_G(const float* __restrict__ fc_w, const float* __restrict__ fc_b,
                             const float* __restrict__ w_nt, float* __restrict__ G) {
    int t = blockIdx.x;
    int i = threadIdx.x;
    float a0 = 0.f, a1 = 0.f, a2 = 0.f;
#pragma unroll 8
    for (int j = 0; j < H; ++j) {
        float w = w_nt[((size_t)t * H + j) * H + i];
        a0 += fc_w[j] * w;          // fc_w[0][j]
        a1 += fc_w[H + j] * w;      // fc_w[1][j]
        a2 += fc_b[j] * w;
    }
    G[(t * 3 + 0) * H + i] = a0;
    G[(t * 3 + 1) * H + i] = a1;
    G[(t * 3 + 2) * H + i] = a2;
}

// ---------------------------------------------------------------------------
// K1b: C[((t*8+r)*3+c)*128+o] = sum_i G[t][c][i] * w_rel[r][i][o]
// Grid: 16 blocks (t*8+r), 128 threads (o). Coalesced w_rel reads; G entries
// are wave-uniform broadcast loads (L1/L2 hit).
// ---------------------------------------------------------------------------
__global__ void precompute_C2(const float* __restrict__ G, const float* __restrict__ w_rel,
                              float* __restrict__ C) {
    int tr = blockIdx.x;            // t*8+r
    int t = tr >> 3, r = tr & 7;
    int o = threadIdx.x;
    const float* g0 = G + (t * 3 + 0) * H;
    const float* g1 = G + (t * 3 + 1) * H;
    const float* g2 = G + (t * 3 + 2) * H;
    float a0 = 0.f, a1 = 0.f, a2 = 0.f;
#pragma unroll 8
    for (int i = 0; i < H; ++i) {
        float w = w_rel[((size_t)r * H + i) * H + o];
        a0 += g0[i] * w;
        a1 += g1[i] * w;
        a2 += g2[i] * w;
    }
    C[((size_t)tr * 3 + 0) * H + o] = a0;
    C[((size_t)tr * 3 + 1) * H + o] = a1;
    C[((size_t)tr * 3 + 2) * H + o] = a2;
}

// ---------------------------------------------------------------------------
// K2: per-edge scatter of (norm*c0, norm*c1, norm) into S[dst][t*8+r][3]
// 3 atomics/edge instead of 128.
// ---------------------------------------------------------------------------
__global__ void edge_scatter(const int* __restrict__ src, const int* __restrict__ dst,
                             const int* __restrict__ etype, const float* __restrict__ norm,
                             const int* __restrict__ node_type, const float* __restrict__ ntc,
                             float* __restrict__ S, int E) {
    int e = blockIdx.x * 256 + threadIdx.x;
    if (e >= E) return;
    int s = src[e];
    int d = dst[e];
    int r = etype[e];
    float nm = norm[e];
    int t = node_type[s];
    float2 c = ((const float2*)ntc)[s];
    float* p = S + (size_t)d * 48 + (t * 8 + r) * 3;
    atomicAdd(p, nm * c.x);
    atomicAdd(p + 1, nm * c.y);
    atomicAdd(p + 2, nm);
}

// ---------------------------------------------------------------------------
// K3: h[v] = relu(S[v,0:48] @ C[48,128]); also pred[v]=clamp(sigmoid(h.fc2_w+b))
// and gsum += h (for mean_nodes). 32 nodes/block, 8 threads/node, 16 out/thread
// as 4 float4 groups o = q*32 + sub*4 (bank-conflict-free C reads).
// ---------------------------------------------------------------------------
__global__ void node_kernel(const float* __restrict__ S, const float* __restrict__ C,
                            const float* __restrict__ fc2_w, const float* __restrict__ fc2_b,
                            float* __restrict__ h, float* __restrict__ pred,
                            float* __restrict__ gsum, int N) {
    __shared__ float Csh[48 * 128];
    __shared__ float Ssh[32 * 49];   // pad 48->49 to spread banks
    __shared__ float gloc[128];
    int tid = threadIdx.x;
    for (int i = tid; i < 48 * 128; i += 256) Csh[i] = C[i];
    int base = blockIdx.x * 32;
    for (int i = tid; i < 32 * 48; i += 256) {
        int vl = i / 48, k = i - vl * 48;
        int v = base + vl;
        Ssh[vl * 49 + k] = (v < N) ? S[(size_t)v * 48 + k] : 0.0f;
    }
    if (tid < 128) gloc[tid] = 0.0f;
    __syncthreads();

    int sub = tid & 7, vl = tid >> 3;
    int v = base + vl;
    float4 hv[4];
#pragma unroll
    for (int q = 0; q < 4; ++q) hv[q] = make_float4(0.f, 0.f, 0.f, 0.f);
    const float* Srow = Ssh + vl * 49;
#pragma unroll 4
    for (int k = 0; k < 48; ++k) {
        float sv = Srow[k];
        const float4* Cr = (const float4*)(Csh + k * 128);
#pragma unroll
        for (int q = 0; q < 4; ++q) {
            float4 c = Cr[q * 8 + sub];
            hv[q].x += sv * c.x; hv[q].y += sv * c.y;
            hv[q].z += sv * c.z; hv[q].w += sv * c.w;
        }
    }
    // relu
#pragma unroll
    for (int q = 0; q < 4; ++q) {
        hv[q].x = fmaxf(hv[q].x, 0.f); hv[q].y = fmaxf(hv[q].y, 0.f);
        hv[q].z = fmaxf(hv[q].z, 0.f); hv[q].w = fmaxf(hv[q].w, 0.f);
    }
    float pd = 0.f;
    if (v < N) {
        float4* hrow = (float4*)(h + (size_t)v * H);
        const float4* w4 = (const float4*)fc2_w;
#pragma unroll
        for (int q = 0; q < 4; ++q) {
            hrow[q * 8 + sub] = hv[q];
            float4 w = w4[q * 8 + sub];
            pd += hv[q].x * w.x + hv[q].y * w.y + hv[q].z * w.z + hv[q].w * w.w;
        }
    }
    // pred: reduce pd over the 8 sub-threads of this node
#pragma unroll
    for (int off = 4; off > 0; off >>= 1) pd += __shfl_down(pd, off, 8);
    if (sub == 0 && v < N) {
        float z = pd + fc2_b[0];
        pred[v] = fminf(fmaxf(fsig(z), 1e-7f), 1e10f);
    }
    // gsum: wave-level pre-reduce over vl (lanes stride 8), then LDS, then global
#pragma unroll
    for (int q = 0; q < 4; ++q) {
        float4 x = (v < N) ? hv[q] : make_float4(0.f, 0.f, 0.f, 0.f);
#pragma unroll
        for (int d = 8; d < 64; d <<= 1) {
            x.x += __shfl_down(x.x, d, 64); x.y += __shfl_down(x.y, d, 64);
            x.z += __shfl_down(x.z, d, 64); x.w += __shfl_down(x.w, d, 64);
        }
        if ((tid & 63) < 8) {
            int o = q * 32 + sub * 4;
            atomicAdd(&gloc[o], x.x); atomicAdd(&gloc[o + 1], x.y);
            atomicAdd(&gloc[o + 2], x.z); atomicAdd(&gloc[o + 3], x.w);
        }
    }
    __syncthreads();
    if (tid < 128) atomicAdd(&gsum[tid], gloc[tid]);
}

// ---------------------------------------------------------------------------
// K4: prob3_sum = sum sigmoid(h[N,128] @ fl3_w[128,1000] + fl3_b)
// 128x128 tile, 8x8 micro, k staged in 32-chunks (LDS 34.8KB -> 4 blocks/CU).
// ---------------------------------------------------------------------------
#define FMA4(A, s, W) { (A).x += (s)*(W).x; (A).y += (s)*(W).y; (A).z += (s)*(W).z; (A).w += (s)*(W).w; }

__global__ __launch_bounds__(256) void prob3_kernel(const float* __restrict__ h,
                                                    const float* __restrict__ w,
                                                    const float* __restrict__ bias,
                                                    float* __restrict__ out, int N) {
    __shared__ float hsh[128 * 36];  // [i][k] pad 32->36 (bank spread, f4-aligned)
    __shared__ float wsh[32 * 128];  // [k][p]
    int tid = threadIdx.x;
    int bp = blockIdx.x & 7;
    int bn = blockIdx.x >> 3;
    int n0 = bn * 128, p0 = bp * 128;
    int tx = tid & 15, ty = tid >> 4;

    float4 acc[8][2];
#pragma unroll
    for (int ii = 0; ii < 8; ++ii) {
        acc[ii][0] = make_float4(0.f, 0.f, 0.f, 0.f);
        acc[ii][1] = make_float4(0.f, 0.f, 0.f, 0.f);
    }

    for (int st = 0; st < 4; ++st) {
        __syncthreads();
        // stage h: rows i=0..127, k = st*32 .. +31
        for (int l = tid; l < 1024; l += 256) {
            int i = l >> 3, kq = l & 7;
            int v = n0 + i;
            float4 val = make_float4(0.f, 0.f, 0.f, 0.f);
            if (v < N) val = *(const float4*)(h + (size_t)v * H + st * 32 + kq * 4);
            *(float4*)(hsh + i * 36 + kq * 4) = val;
        }
        // stage w: k rows st*32..+31, p = p0..p0+127
        for (int l = tid; l < 1024; l += 256) {
            int kl = l >> 5, pq = l & 31;
            int p = p0 + pq * 4;
            float4 val = make_float4(0.f, 0.f, 0.f, 0.f);
            if (p < PNUM) val = *(const float4*)(w + (size_t)(st * 32 + kl) * PNUM + p);
            *(float4*)(wsh + kl * 128 + pq * 4) = val;
        }
        __syncthreads();
#pragma unroll
        for (int ks = 0; ks < 32; ks += 4) {
            float4 wv[4][2];
#pragma unroll
            for (int kk = 0; kk < 4; ++kk) {
                wv[kk][0] = *(const float4*)(wsh + (ks + kk) * 128 + tx * 4);
                wv[kk][1] = *(const float4*)(wsh + (ks + kk) * 128 + 64 + tx * 4);
            }
#pragma unroll
            for (int ii = 0; ii < 8; ++ii) {
                float4 a = *(const float4*)(hsh + (ty + 16 * ii) * 36 + ks);
                FMA4(acc[ii][0], a.x, wv[0][0]); FMA4(acc[ii][1], a.x, wv[0][1]);
                FMA4(acc[ii][0], a.y, wv[1][0]); FMA4(acc[ii][1], a.y, wv[1][1]);
                FMA4(acc[ii][0], a.z, wv[2][0]); FMA4(acc[ii][1], a.z, wv[2][1]);
                FMA4(acc[ii][0], a.w, wv[3][0]); FMA4(acc[ii][1], a.w, wv[3][1]);
            }
        }
    }

    float lsum = 0.f;
#pragma unroll
    for (int ii = 0; ii < 8; ++ii) {
        int v = n0 + ty + 16 * ii;
        if (v < N) {
#pragma unroll
            for (int g = 0; g < 2; ++g) {
                int pb = p0 + g * 64 + tx * 4;
#pragma unroll
                for (int q = 0; q < 4; ++q) {
                    int p = pb + q;
                    if (p < PNUM) lsum += fsig(f4c(acc[ii][g], q) + bias[p]);
                }
            }
        }
    }
    lsum = wave_reduce(lsum);
    if ((tid & 63) == 0) atomicAdd(out + 5, lsum);
}

// ---------------------------------------------------------------------------
// K5: agg[dst] += pred[src]
// ---------------------------------------------------------------------------
__global__ void agg_edges(const int* __restrict__ src, const int* __restrict__ dst,
                          const float* __restrict__ pred, float* __restrict__ agg, int E) {
    int e = blockIdx.x * 256 + threadIdx.x;
    if (e >= E) return;
    atomicAdd(&agg[dst[e]], pred[src[e]]);
}

// K6: out_cost = sum (agg-1)^2 * special_cost
__global__ void outcost_kernel(const float* __restrict__ agg, const float* __restrict__ sc,
                               float* __restrict__ out, int N) {
    int i = blockIdx.x * 256 + threadIdx.x;
    float v = 0.f;
    if (i < N) { float d = agg[i] - 1.0f; v = d * d * sc[i]; }
    v = wave_reduce(v);
    if ((threadIdx.x & 63) == 0) atomicAdd(out + 4, v);
}

// K7: row sums rs[i], col sums cs[j] of pm = pred[:M*M]
__global__ void rowcol_kernel(const float* __restrict__ pred, float* __restrict__ rs,
                              float* __restrict__ cs) {
    int i = blockIdx.x;
    int j = threadIdx.x;
    float p = (j < MNUM) ? pred[i * MNUM + j] : 0.0f;
    if (j < MNUM) atomicAdd(&cs[j], p);
    float s = wave_reduce(p);
    if ((j & 63) == 0) atomicAdd(&rs[i], s);
}

// K8: ce and loss2
__global__ void losses_kernel(const float* __restrict__ pred, const float* __restrict__ gt,
                              const float* __restrict__ rs, const float* __restrict__ cs,
                              float* __restrict__ out) {
    int idx = blockIdx.x * 256 + threadIdx.x;
    float ce = 0.f, l2 = 0.f;
    if (idx < MNUM * MNUM) {
        int i = idx / MNUM, j = idx - i * MNUM;
        float p = pred[idx];
        ce = -gt[idx] * __log2f(p);
        l2 = p * (rs[i] + cs[j] - 2.0f * p);
    }
    ce = wave_reduce(ce);
    l2 = wave_reduce(l2);
    if ((threadIdx.x & 63) == 0) { atomicAdd(out + 3, ce); atomicAdd(out + 2, l2); }
}

// K9: sumone = sum (rs-1)^2 + (cs-1)^2
__global__ void sumone_kernel(const float* __restrict__ rs, const float* __restrict__ cs,
                              float* __restrict__ out) {
    int j = threadIdx.x;
    float v = 0.f;
    if (j < MNUM) {
        float a = rs[j] - 1.0f, b = cs[j] - 1.0f;
        v = a * a + b * b;
    }
    v = wave_reduce(v);
    if ((j & 63) == 0) atomicAdd(out + 1, v);
}

// K10: pred_obj = mean(h) @ fc3_w + fc3_b
__global__ void final_kernel(const float* __restrict__ gsum, const float* __restrict__ fc3_w,
                             const float* __restrict__ fc3_b, float* __restrict__ out, int N) {
    int t = threadIdx.x;  // 64 threads
    float invN = 1.0f / (float)N;
    float v = gsum[t] * invN * fc3_w[t] + gsum[t + 64] * invN * fc3_w[t + 64];
    v = wave_reduce(v);
    if (t == 0) out[0] = v + fc3_b[0];
}

extern "C" void kernel_launch(void* const* d_in, const int* in_sizes, int n_in,
                              void* d_out, int out_size, void* d_ws, size_t ws_size,
                              hipStream_t stream) {
    const float* ntc   = (const float*)d_in[0];
    const float* norm  = (const float*)d_in[1];
    const float* sc    = (const float*)d_in[2];
    const float* gt    = (const float*)d_in[3];
    const float* fc_w  = (const float*)d_in[4];
    const float* fc_b  = (const float*)d_in[5];
    const float* w_nt  = (const float*)d_in[6];
    const float* w_rel = (const float*)d_in[7];
    const float* fc2_w = (const float*)d_in[8];
    const float* fc2_b = (const float*)d_in[9];
    const float* fc3_w = (const float*)d_in[10];
    const float* fc3_b = (const float*)d_in[11];
    const float* fl3_w = (const float*)d_in[12];
    const float* fl3_b = (const float*)d_in[13];
    const int* node_type = (const int*)d_in[14];
    const int* src   = (const int*)d_in[15];
    const int* dst   = (const int*)d_in[16];
    const int* etype = (const int*)d_in[17];
    int N = in_sizes[2];
    int E = in_sizes[1];

    float* ws   = (float*)d_ws;
    float* C    = ws;                 // 6144
    float* gsum = ws + 6144;          // 128
    float* rs   = ws + 6272;          // 256 (223 used)
    float* cs   = ws + 6528;          // 256
    float* G    = ws + 6784;          // 768 (2 types x 3 coefs x 128)
    float* pred = ws + 7552;          // N
    float* agg  = pred + N;           // N
    float* S    = agg + N;            // N*48
    float* h    = S + (size_t)N * 48; // N*128
    float* out  = (float*)d_out;

    hipMemsetAsync(d_out, 0, 6 * sizeof(float), stream);
    // zero gsum, rs, cs, G, pred, agg, S (contiguous): 1408 + 50*N floats
    hipMemsetAsync(gsum, 0, (size_t)(1408 + 50 * (size_t)N) * sizeof(float), stream);

    precompute_G<<<2, 128, 0, stream>>>(fc_w, fc_b, w_nt, G);
    precompute_C2<<<16, 128, 0, stream>>>(G, w_rel, C);
    edge_scatter<<<(E + 255) / 256, 256, 0, stream>>>(src, dst, etype, norm, node_type, ntc, S, E);
    node_kernel<<<(N + 31) / 32, 256, 0, stream>>>(S, C, fc2_w, fc2_b, h, pred, gsum, N);
    prob3_kernel<<<((N + 127) / 128) * 8, 256, 0, stream>>>(h, fl3_w, fl3_b, out, N);
    agg_edges<<<(E + 255) / 256, 256, 0, stream>>>(src, dst, pred, agg, E);
    outcost_kernel<<<(N + 255) / 256, 256, 0, stream>>>(agg, sc, out, N);
    rowcol_kernel<<<MNUM, 256, 0, stream>>>(pred, rs, cs);
    losses_kernel<<<(MNUM * MNUM + 255) / 256, 256, 0, stream>>>(pred, gt, rs, cs, out);
    sumone_kernel<<<1, 256, 0, stream>>>(rs, cs, out);
    final_kernel<<<1, 64, 0, stream>>>(gsum, fc3_w, fc3_b, out, N);
}

// Round 3
// 732.314 us; speedup vs baseline: 1.7151x; 1.1053x over previous
//
#include <hip/hip_runtime.h>

#define H 128
#define RNUM 8
#define TNUM 2
#define PNUM 1000
#define MNUM 223

typedef __attribute__((ext_vector_type(8))) short bf16x8;
typedef __attribute__((ext_vector_type(4))) float f32x4;

__device__ __forceinline__ float fsig(float z) {
    return 1.0f / (1.0f + __expf(-z));
}

__device__ __forceinline__ float wave_reduce(float v) {
#pragma unroll
    for (int off = 32; off > 0; off >>= 1) v += __shfl_down(v, off, 64);
    return v;
}

__device__ __forceinline__ unsigned short f2bf(float f) {
    unsigned int u = __float_as_uint(f);
    u += 0x7fffu + ((u >> 16) & 1u);   // RNE
    return (unsigned short)(u >> 16);
}

// ---------------------------------------------------------------------------
// K1a: G[t][c][i] = sum_j coef[c][j] * w_nt[t][j][i], coef rows = fc_w[0],
// fc_w[1], fc_b. Grid: 2 blocks (t), 128 threads (i). Coalesced w_nt reads.
// ---------------------------------------------------------------------------
__global__ void precompute_G(const float* __restrict__ fc_w, const float* __restrict__ fc_b,
                             const float* __restrict__ w_nt, float* __restrict__ G) {
    int t = blockIdx.x;
    int i = threadIdx.x;
    float a0 = 0.f, a1 = 0.f, a2 = 0.f;
#pragma unroll 8
    for (int j = 0; j < H; ++j) {
        float w = w_nt[((size_t)t * H + j) * H + i];
        a0 += fc_w[j] * w;          // fc_w[0][j]
        a1 += fc_w[H + j] * w;      // fc_w[1][j]
        a2 += fc_b[j] * w;
    }
    G[(t * 3 + 0) * H + i] = a0;
    G[(t * 3 + 1) * H + i] = a1;
    G[(t * 3 + 2) * H + i] = a2;
}

// ---------------------------------------------------------------------------
// K1b: C[((t*8+r)*3+c)*128+o] = sum_i G[t][c][i] * w_rel[r][i][o]
// ---------------------------------------------------------------------------
__global__ void precompute_C2(const float* __restrict__ G, const float* __restrict__ w_rel,
                              float* __restrict__ C) {
    int tr = blockIdx.x;            // t*8+r
    int t = tr >> 3, r = tr & 7;
    int o = threadIdx.x;
    const float* g0 = G + (t * 3 + 0) * H;
    const float* g1 = G + (t * 3 + 1) * H;
    const float* g2 = G + (t * 3 + 2) * H;
    float a0 = 0.f, a1 = 0.f, a2 = 0.f;
#pragma unroll 8
    for (int i = 0; i < H; ++i) {
        float w = w_rel[((size_t)r * H + i) * H + o];
        a0 += g0[i] * w;
        a1 += g1[i] * w;
        a2 += g2[i] * w;
    }
    C[((size_t)tr * 3 + 0) * H + o] = a0;
    C[((size_t)tr * 3 + 1) * H + o] = a1;
    C[((size_t)tr * 3 + 2) * H + o] = a2;
}

// ---------------------------------------------------------------------------
// K1c: wt[p][k] = bf16(fl3_w[k][p]), p padded to 1024 with zeros.
// ---------------------------------------------------------------------------
__global__ void wt_kernel(const float* __restrict__ w, unsigned short* __restrict__ wt) {
    int p = blockIdx.x;   // 0..1023
    int k = threadIdx.x;  // 0..127
    float v = (p < PNUM) ? w[(size_t)k * PNUM + p] : 0.0f;
    wt[(size_t)p * H + k] = f2bf(v);
}

// ---------------------------------------------------------------------------
// K2: per-edge scatter of (norm*c0, norm*c1, norm) into S[dst][t*8+r][3]
// ---------------------------------------------------------------------------
__global__ void edge_scatter(const int* __restrict__ src, const int* __restrict__ dst,
                             const int* __restrict__ etype, const float* __restrict__ norm,
                             const int* __restrict__ node_type, const float* __restrict__ ntc,
                             float* __restrict__ S, int E) {
    int e = blockIdx.x * 256 + threadIdx.x;
    if (e >= E) return;
    int s = src[e];
    int d = dst[e];
    int r = etype[e];
    float nm = norm[e];
    int t = node_type[s];
    float2 c = ((const float2*)ntc)[s];
    float* p = S + (size_t)d * 48 + (t * 8 + r) * 3;
    atomicAdd(p, nm * c.x);
    atomicAdd(p + 1, nm * c.y);
    atomicAdd(p + 2, nm);
}

// ---------------------------------------------------------------------------
// K3: h[v] = relu(S[v,0:48] @ C[48,128]) -> bf16; pred[v]; gsum += h.
// ---------------------------------------------------------------------------
__global__ void node_kernel(const float* __restrict__ S, const float* __restrict__ C,
                            const float* __restrict__ fc2_w, const float* __restrict__ fc2_b,
                            unsigned short* __restrict__ hb, float* __restrict__ pred,
                            float* __restrict__ gsum, int N) {
    __shared__ float Csh[48 * 128];
    __shared__ float Ssh[32 * 49];   // pad 48->49 to spread banks
    __shared__ float gloc[128];
    int tid = threadIdx.x;
    for (int i = tid; i < 48 * 128; i += 256) Csh[i] = C[i];
    int base = blockIdx.x * 32;
    for (int i = tid; i < 32 * 48; i += 256) {
        int vl = i / 48, k = i - vl * 48;
        int v = base + vl;
        Ssh[vl * 49 + k] = (v < N) ? S[(size_t)v * 48 + k] : 0.0f;
    }
    if (tid < 128) gloc[tid] = 0.0f;
    __syncthreads();

    int sub = tid & 7, vl = tid >> 3;
    int v = base + vl;
    float4 hv[4];
#pragma unroll
    for (int q = 0; q < 4; ++q) hv[q] = make_float4(0.f, 0.f, 0.f, 0.f);
    const float* Srow = Ssh + vl * 49;
#pragma unroll 4
    for (int k = 0; k < 48; ++k) {
        float sv = Srow[k];
        const float4* Cr = (const float4*)(Csh + k * 128);
#pragma unroll
        for (int q = 0; q < 4; ++q) {
            float4 c = Cr[q * 8 + sub];
            hv[q].x += sv * c.x; hv[q].y += sv * c.y;
            hv[q].z += sv * c.z; hv[q].w += sv * c.w;
        }
    }
#pragma unroll
    for (int q = 0; q < 4; ++q) {
        hv[q].x = fmaxf(hv[q].x, 0.f); hv[q].y = fmaxf(hv[q].y, 0.f);
        hv[q].z = fmaxf(hv[q].z, 0.f); hv[q].w = fmaxf(hv[q].w, 0.f);
    }
    float pd = 0.f;
    if (v < N) {
        unsigned short* hrow = hb + (size_t)v * H;
        const float4* w4 = (const float4*)fc2_w;
#pragma unroll
        for (int q = 0; q < 4; ++q) {
            unsigned int u0 = ((unsigned int)f2bf(hv[q].y) << 16) | f2bf(hv[q].x);
            unsigned int u1 = ((unsigned int)f2bf(hv[q].w) << 16) | f2bf(hv[q].z);
            *(uint2*)(hrow + q * 32 + sub * 4) = make_uint2(u0, u1);
            float4 w = w4[q * 8 + sub];
            pd += hv[q].x * w.x + hv[q].y * w.y + hv[q].z * w.z + hv[q].w * w.w;
        }
    }
#pragma unroll
    for (int off = 4; off > 0; off >>= 1) pd += __shfl_down(pd, off, 8);
    if (sub == 0 && v < N) {
        float z = pd + fc2_b[0];
        pred[v] = fminf(fmaxf(fsig(z), 1e-7f), 1e10f);
    }
#pragma unroll
    for (int q = 0; q < 4; ++q) {
        float4 x = (v < N) ? hv[q] : make_float4(0.f, 0.f, 0.f, 0.f);
#pragma unroll
        for (int d = 8; d < 64; d <<= 1) {
            x.x += __shfl_down(x.x, d, 64); x.y += __shfl_down(x.y, d, 64);
            x.z += __shfl_down(x.z, d, 64); x.w += __shfl_down(x.w, d, 64);
        }
        if ((tid & 63) < 8) {
            int o = q * 32 + sub * 4;
            atomicAdd(&gloc[o], x.x); atomicAdd(&gloc[o + 1], x.y);
            atomicAdd(&gloc[o + 2], x.z); atomicAdd(&gloc[o + 3], x.w);
        }
    }
    __syncthreads();
    if (tid < 128) atomicAdd(&gsum[tid], gloc[tid]);
}

// ---------------------------------------------------------------------------
// K4: prob3_sum via bf16 MFMA. 128x128 tile/block, whole K=128 in LDS.
// 4 waves, each 64x64 quadrant = 4x4 tiles of mfma_f32_16x16x32_bf16.
// LDS rows padded to 136 shorts (stride 68 dwords = 4 mod 32 -> 2-way max).
// Layouts per m89/m120: A[m=lane&15][k=quad*8+j]; D row=quad*4+reg, col=lane&15.
// ---------------------------------------------------------------------------
__global__ __launch_bounds__(256) void prob3_mfma(const unsigned short* __restrict__ hb,
                                                  const unsigned short* __restrict__ wt,
                                                  const float* __restrict__ bias,
                                                  float* __restrict__ out, int N) {
    __shared__ unsigned short Ash[128 * 136];
    __shared__ unsigned short Bsh[128 * 136];
    int tid = threadIdx.x;
    int bp = blockIdx.x & 7;
    int bn = blockIdx.x >> 3;
    int n0 = bn * 128, p0 = bp * 128;

    // stage A (h rows, zero-fill past N) and B (wt rows) as 16B chunks
    {
        int c = tid & 15;        // 16B chunk within row (8 shorts)
        int r0 = tid >> 4;       // rows 0..15, step 16
        for (int it = 0; it < 8; ++it) {
            int row = r0 + it * 16;
            int v = n0 + row;
            uint4 av = make_uint4(0u, 0u, 0u, 0u);
            if (v < N) av = *(const uint4*)(hb + (size_t)v * H + c * 8);
            *(uint4*)(Ash + row * 136 + c * 8) = av;
            uint4 bv = *(const uint4*)(wt + (size_t)(p0 + row) * H + c * 8);
            *(uint4*)(Bsh + row * 136 + c * 8) = bv;
        }
    }
    __syncthreads();

    int lane = tid & 63, wid = tid >> 6;
    int wy = wid >> 1, wx = wid & 1;
    int lrow = lane & 15, quad = lane >> 4;

    f32x4 acc[4][4];
#pragma unroll
    for (int tm = 0; tm < 4; ++tm)
#pragma unroll
        for (int tn = 0; tn < 4; ++tn)
            acc[tm][tn] = (f32x4){0.f, 0.f, 0.f, 0.f};

    const unsigned short* Abase = Ash + (wy * 64 + lrow) * 136 + quad * 8;
    const unsigned short* Bbase = Bsh + (wx * 64 + lrow) * 136 + quad * 8;
#pragma unroll
    for (int ks = 0; ks < 4; ++ks) {
        bf16x8 a[4], b[4];
#pragma unroll
        for (int t = 0; t < 4; ++t) {
            a[t] = *(const bf16x8*)(Abase + t * 16 * 136 + ks * 32);
            b[t] = *(const bf16x8*)(Bbase + t * 16 * 136 + ks * 32);
        }
#pragma unroll
        for (int tm = 0; tm < 4; ++tm)
#pragma unroll
            for (int tn = 0; tn < 4; ++tn)
                acc[tm][tn] = __builtin_amdgcn_mfma_f32_16x16x32_bf16(a[tm], b[tn], acc[tm][tn], 0, 0, 0);
    }

    float lsum = 0.f;
#pragma unroll
    for (int tn = 0; tn < 4; ++tn) {
        int p = p0 + wx * 64 + tn * 16 + lrow;
        if (p < PNUM) {
            float bv = bias[p];
#pragma unroll
            for (int tm = 0; tm < 4; ++tm) {
                int nb = n0 + wy * 64 + tm * 16 + quad * 4;
#pragma unroll
                for (int r = 0; r < 4; ++r) {
                    if (nb + r < N) lsum += fsig(acc[tm][tn][r] + bv);
                }
            }
        }
    }
    lsum = wave_reduce(lsum);
    if (lane == 0) atomicAdd(out + 5, lsum);
}

// ---------------------------------------------------------------------------
// K5: agg[dst] += pred[src]
// ---------------------------------------------------------------------------
__global__ void agg_edges(const int* __restrict__ src, const int* __restrict__ dst,
                          const float* __restrict__ pred, float* __restrict__ agg, int E) {
    int e = blockIdx.x * 256 + threadIdx.x;
    if (e >= E) return;
    atomicAdd(&agg[dst[e]], pred[src[e]]);
}

// K6: out_cost = sum (agg-1)^2 * special_cost
__global__ void outcost_kernel(const float* __restrict__ agg, const float* __restrict__ sc,
                               float* __restrict__ out, int N) {
    int i = blockIdx.x * 256 + threadIdx.x;
    float v = 0.f;
    if (i < N) { float d = agg[i] - 1.0f; v = d * d * sc[i]; }
    v = wave_reduce(v);
    if ((threadIdx.x & 63) == 0) atomicAdd(out + 4, v);
}

// K7: row sums rs[i], col sums cs[j] of pm = pred[:M*M]
__global__ void rowcol_kernel(const float* __restrict__ pred, float* __restrict__ rs,
                              float* __restrict__ cs) {
    int i = blockIdx.x;
    int j = threadIdx.x;
    float p = (j < MNUM) ? pred[i * MNUM + j] : 0.0f;
    if (j < MNUM) atomicAdd(&cs[j], p);
    float s = wave_reduce(p);
    if ((j & 63) == 0) atomicAdd(&rs[i], s);
}

// K8: ce and loss2
__global__ void losses_kernel(const float* __restrict__ pred, const float* __restrict__ gt,
                              const float* __restrict__ rs, const float* __restrict__ cs,
                              float* __restrict__ out) {
    int idx = blockIdx.x * 256 + threadIdx.x;
    float ce = 0.f, l2 = 0.f;
    if (idx < MNUM * MNUM) {
        int i = idx / MNUM, j = idx - i * MNUM;
        float p = pred[idx];
        ce = -gt[idx] * __log2f(p);
        l2 = p * (rs[i] + cs[j] - 2.0f * p);
    }
    ce = wave_reduce(ce);
    l2 = wave_reduce(l2);
    if ((threadIdx.x & 63) == 0) { atomicAdd(out + 3, ce); atomicAdd(out + 2, l2); }
}

// K9: sumone = sum (rs-1)^2 + (cs-1)^2
__global__ void sumone_kernel(const float* __restrict__ rs, const float* __restrict__ cs,
                              float* __restrict__ out) {
    int j = threadIdx.x;
    float v = 0.f;
    if (j < MNUM) {
        float a = rs[j] - 1.0f, b = cs[j] - 1.0f;
        v = a * a + b * b;
    }
    v = wave_reduce(v);
    if ((j & 63) == 0) atomicAdd(out + 1, v);
}

// K10: pred_obj = mean(h) @ fc3_w + fc3_b
__global__ void final_kernel(const float* __restrict__ gsum, const float* __restrict__ fc3_w,
                             const float* __restrict__ fc3_b, float* __restrict__ out, int N) {
    int t = threadIdx.x;  // 64 threads
    float invN = 1.0f / (float)N;
    float v = gsum[t] * invN * fc3_w[t] + gsum[t + 64] * invN * fc3_w[t + 64];
    v = wave_reduce(v);
    if (t == 0) out[0] = v + fc3_b[0];
}

extern "C" void kernel_launch(void* const* d_in, const int* in_sizes, int n_in,
                              void* d_out, int out_size, void* d_ws, size_t ws_size,
                              hipStream_t stream) {
    const float* ntc   = (const float*)d_in[0];
    const float* norm  = (const float*)d_in[1];
    const float* sc    = (const float*)d_in[2];
    const float* gt    = (const float*)d_in[3];
    const float* fc_w  = (const float*)d_in[4];
    const float* fc_b  = (const float*)d_in[5];
    const float* w_nt  = (const float*)d_in[6];
    const float* w_rel = (const float*)d_in[7];
    const float* fc2_w = (const float*)d_in[8];
    const float* fc2_b = (const float*)d_in[9];
    const float* fc3_w = (const float*)d_in[10];
    const float* fc3_b = (const float*)d_in[11];
    const float* fl3_w = (const float*)d_in[12];
    const float* fl3_b = (const float*)d_in[13];
    const int* node_type = (const int*)d_in[14];
    const int* src   = (const int*)d_in[15];
    const int* dst   = (const int*)d_in[16];
    const int* etype = (const int*)d_in[17];
    int N = in_sizes[2];
    int E = in_sizes[1];

    float* ws   = (float*)d_ws;
    float* C    = ws;                               // 6144
    float* G    = ws + 6144;                        // 768
    unsigned short* wt = (unsigned short*)(ws + 6912);  // 1024*128 bf16 = 65536 fl
    float* pred = ws + 72448;                       // N
    float* gsum = pred + N;                         // 128
    float* rs   = gsum + 128;                       // 256 (223 used)
    float* cs   = rs + 256;                         // 256
    float* agg  = cs + 256;                         // N
    float* S    = agg + N;                          // 48N
    unsigned short* hb = (unsigned short*)(S + (size_t)N * 48);  // N*128 bf16
    float* out  = (float*)d_out;

    hipMemsetAsync(d_out, 0, 6 * sizeof(float), stream);
    // zero gsum, rs, cs, agg, S (contiguous): 640 + 49N floats
    hipMemsetAsync(gsum, 0, (size_t)(640 + 49 * (size_t)N) * sizeof(float), stream);

    precompute_G<<<2, 128, 0, stream>>>(fc_w, fc_b, w_nt, G);
    precompute_C2<<<16, 128, 0, stream>>>(G, w_rel, C);
    wt_kernel<<<1024, 128, 0, stream>>>(fl3_w, wt);
    edge_scatter<<<(E + 255) / 256, 256, 0, stream>>>(src, dst, etype, norm, node_type, ntc, S, E);
    node_kernel<<<(N + 31) / 32, 256, 0, stream>>>(S, C, fc2_w, fc2_b, hb, pred, gsum, N);
    prob3_mfma<<<((N + 127) / 128) * 8, 256, 0, stream>>>(hb, wt, fl3_b, out, N);
    agg_edges<<<(E + 255) / 256, 256, 0, stream>>>(src, dst, pred, agg, E);
    outcost_kernel<<<(N + 255) / 256, 256, 0, stream>>>(agg, sc, out, N);
    rowcol_kernel<<<MNUM, 256, 0, stream>>>(pred, rs, cs);
    losses_kernel<<<(MNUM * MNUM + 255) / 256, 256, 0, stream>>>(pred, gt, rs, cs, out);
    sumone_kernel<<<1, 256, 0, stream>>>(rs, cs, out);
    final_kernel<<<1, 64, 0, stream>>>(gsum, fc3_w, fc3_b, out, N);
}

// Round 5
// 337.890 us; speedup vs baseline: 3.7172x; 2.1673x over previous
//
#include <hip/hip_runtime.h>

#define H 128
#define RNUM 8
#define TNUM 2
#define PNUM 1000
#define MNUM 223
#define BNODES 200          // nodes per dst-bucket
#define BCAP 7168           // payload capacity per bucket (mean 6400, +9.6 sigma)

typedef __attribute__((ext_vector_type(8))) short bf16x8;
typedef __attribute__((ext_vector_type(4))) float f32x4;

__device__ __forceinline__ float fsig(float z) {
    return 1.0f / (1.0f + __expf(-z));
}

__device__ __forceinline__ float wave_reduce(float v) {
#pragma unroll
    for (int off = 32; off > 0; off >>= 1) v += __shfl_down(v, off, 64);
    return v;
}

__device__ __forceinline__ unsigned short f2bf(float f) {
    unsigned int u = __float_as_uint(f);
    u += 0x7fffu + ((u >> 16) & 1u);   // RNE
    return (unsigned short)(u >> 16);
}

// ---------------------------------------------------------------------------
// K1a: G[t][c][i] = sum_j coef[c][j] * w_nt[t][j][i]
// ---------------------------------------------------------------------------
__global__ void precompute_G(const float* __restrict__ fc_w, const float* __restrict__ fc_b,
                             const float* __restrict__ w_nt, float* __restrict__ G) {
    int t = blockIdx.x;
    int i = threadIdx.x;
    float a0 = 0.f, a1 = 0.f, a2 = 0.f;
#pragma unroll 8
    for (int j = 0; j < H; ++j) {
        float w = w_nt[((size_t)t * H + j) * H + i];
        a0 += fc_w[j] * w;
        a1 += fc_w[H + j] * w;
        a2 += fc_b[j] * w;
    }
    G[(t * 3 + 0) * H + i] = a0;
    G[(t * 3 + 1) * H + i] = a1;
    G[(t * 3 + 2) * H + i] = a2;
}

// ---------------------------------------------------------------------------
// K1b: C[((t*8+r)*3+c)*128+o] = sum_i G[t][c][i] * w_rel[r][i][o]
// ---------------------------------------------------------------------------
__global__ void precompute_C2(const float* __restrict__ G, const float* __restrict__ w_rel,
                              float* __restrict__ C) {
    int tr = blockIdx.x;            // t*8+r
    int t = tr >> 3, r = tr & 7;
    int o = threadIdx.x;
    const float* g0 = G + (t * 3 + 0) * H;
    const float* g1 = G + (t * 3 + 1) * H;
    const float* g2 = G + (t * 3 + 2) * H;
    float a0 = 0.f, a1 = 0.f, a2 = 0.f;
#pragma unroll 8
    for (int i = 0; i < H; ++i) {
        float w = w_rel[((size_t)r * H + i) * H + o];
        a0 += g0[i] * w;
        a1 += g1[i] * w;
        a2 += g2[i] * w;
    }
    C[((size_t)tr * 3 + 0) * H + o] = a0;
    C[((size_t)tr * 3 + 1) * H + o] = a1;
    C[((size_t)tr * 3 + 2) * H + o] = a2;
}

// ---------------------------------------------------------------------------
// K1c: wt[p][k] = bf16(fl3_w[k][p]), p padded to 1024 with zeros.
// ---------------------------------------------------------------------------
__global__ void wt_kernel(const float* __restrict__ w, unsigned short* __restrict__ wt) {
    int p = blockIdx.x;   // 0..1023
    int k = threadIdx.x;  // 0..127
    float v = (p < PNUM) ? w[(size_t)k * PNUM + p] : 0.0f;
    wt[(size_t)p * H + k] = f2bf(v);
}

// ---------------------------------------------------------------------------
// K2: partition edges into dst-range buckets. Payload 8B:
//   .x = src | (local<<18) | (r<<26) | (t<<29)   .y = bits(norm)
// LDS histogram -> 1 global atomic per (block,bucket) -> positioned append.
// ---------------------------------------------------------------------------
__global__ __launch_bounds__(1024) void partition_kernel(
        const int* __restrict__ src, const int* __restrict__ dst,
        const int* __restrict__ etype, const float* __restrict__ norm,
        const int* __restrict__ node_type, int* __restrict__ cursor,
        uint2* __restrict__ buck, int E) {
    __shared__ int lh[256];
    __shared__ int gb[256];
    int tid = threadIdx.x;
    if (tid < 256) lh[tid] = 0;
    __syncthreads();
    int e = blockIdx.x * 1024 + tid;
    int b = 0, rank = 0;
    uint2 pl;
    bool act = (e < E);
    if (act) {
        int s = src[e];
        int d = dst[e];
        int r = etype[e];
        float nm = norm[e];
        int t = node_type[s];
        b = d / BNODES;
        int local = d - b * BNODES;
        pl.x = (unsigned)s | ((unsigned)local << 18) | ((unsigned)r << 26) | ((unsigned)t << 29);
        pl.y = __float_as_uint(nm);
        rank = atomicAdd(&lh[b], 1);
    }
    __syncthreads();
    if (tid < 256 && lh[tid] > 0) {
        int g = atomicAdd(&cursor[tid], lh[tid]);
        gb[tid] = (g < 0) ? 0 : (g > BCAP ? BCAP : g);   // harden vs corruption
    }
    __syncthreads();
    if (act) {
        int pos = gb[b] + rank;
        if (pos < BCAP) buck[(size_t)b * BCAP + pos] = pl;
    }
}

// ---------------------------------------------------------------------------
// K3: per-bucket: replay edges -> S[200][49] in LDS (LDS atomics), then
// h = relu(S@C) for the bucket's 200 nodes; write hb (bf16), pred, gsum.
// ---------------------------------------------------------------------------
__global__ __launch_bounds__(256) void bucket_node(
        const uint2* __restrict__ buck, const int* __restrict__ cursor,
        const float* __restrict__ ntc, const float* __restrict__ C,
        const float* __restrict__ fc2_w, const float* __restrict__ fc2_b,
        unsigned short* __restrict__ hb, float* __restrict__ pred,
        float* __restrict__ gsum, int N) {
    __shared__ float S[224 * 49];    // 43.9KB (224 covers 7x32 node iter, pad 49)
    __shared__ float Csh[48 * 128];  // 24.6KB
    __shared__ float gloc[128];
    int tid = threadIdx.x;
    int bkt = blockIdx.x;
    for (int i = tid; i < 224 * 49; i += 256) S[i] = 0.0f;
    for (int i = tid; i < 48 * 128; i += 256) Csh[i] = C[i];
    if (tid < 128) gloc[tid] = 0.0f;
    __syncthreads();

    int cnt = cursor[bkt];
    if (cnt > BCAP) cnt = BCAP;
    if (cnt < 0) cnt = 0;
    const uint2* bp = buck + (size_t)bkt * BCAP;
    for (int i = tid; i < cnt; i += 256) {
        uint2 pl = bp[i];
        int s = pl.x & 0x3FFFF;
        int local = (pl.x >> 18) & 0xFF;
        int r = (pl.x >> 26) & 7;
        int t = (pl.x >> 29) & 1;
        float nm = __uint_as_float(pl.y);
        float2 c = ((const float2*)ntc)[s];
        float* p = &S[local * 49 + (t * 8 + r) * 3];
        atomicAdd(p, nm * c.x);
        atomicAdd(p + 1, nm * c.y);
        atomicAdd(p + 2, nm);
    }
    __syncthreads();

    int base = bkt * BNODES;
    int sub = tid & 7, vl = tid >> 3;
    const float4* w4 = (const float4*)fc2_w;
    for (int iter = 0; iter < 7; ++iter) {
        int ln = iter * 32 + vl;
        int v = base + ln;
        bool act = (ln < BNODES) && (v < N);
        float4 hv[4];
#pragma unroll
        for (int q = 0; q < 4; ++q) hv[q] = make_float4(0.f, 0.f, 0.f, 0.f);
        const float* Srow = S + ln * 49;
#pragma unroll 4
        for (int k = 0; k < 48; ++k) {
            float sv = Srow[k];
            const float4* Cr = (const float4*)(Csh + k * 128);
#pragma unroll
            for (int q = 0; q < 4; ++q) {
                float4 c = Cr[q * 8 + sub];
                hv[q].x += sv * c.x; hv[q].y += sv * c.y;
                hv[q].z += sv * c.z; hv[q].w += sv * c.w;
            }
        }
#pragma unroll
        for (int q = 0; q < 4; ++q) {
            hv[q].x = fmaxf(hv[q].x, 0.f); hv[q].y = fmaxf(hv[q].y, 0.f);
            hv[q].z = fmaxf(hv[q].z, 0.f); hv[q].w = fmaxf(hv[q].w, 0.f);
        }
        float pd = 0.f;
        if (act) {
            unsigned short* hrow = hb + (size_t)v * H;
#pragma unroll
            for (int q = 0; q < 4; ++q) {
                unsigned int u0 = ((unsigned int)f2bf(hv[q].y) << 16) | f2bf(hv[q].x);
                unsigned int u1 = ((unsigned int)f2bf(hv[q].w) << 16) | f2bf(hv[q].z);
                *(uint2*)(hrow + q * 32 + sub * 4) = make_uint2(u0, u1);
                float4 w = w4[q * 8 + sub];
                pd += hv[q].x * w.x + hv[q].y * w.y + hv[q].z * w.z + hv[q].w * w.w;
            }
        }
#pragma unroll
        for (int off = 4; off > 0; off >>= 1) pd += __shfl_down(pd, off, 8);
        if (sub == 0 && act) {
            float z = pd + fc2_b[0];
            pred[v] = fminf(fmaxf(fsig(z), 1e-7f), 1e10f);
        }
#pragma unroll
        for (int q = 0; q < 4; ++q) {
            float4 x = act ? hv[q] : make_float4(0.f, 0.f, 0.f, 0.f);
#pragma unroll
            for (int d = 8; d < 64; d <<= 1) {
                x.x += __shfl_down(x.x, d, 64); x.y += __shfl_down(x.y, d, 64);
                x.z += __shfl_down(x.z, d, 64); x.w += __shfl_down(x.w, d, 64);
            }
            if ((tid & 63) < 8) {
                int o = q * 32 + sub * 4;
                atomicAdd(&gloc[o], x.x); atomicAdd(&gloc[o + 1], x.y);
                atomicAdd(&gloc[o + 2], x.z); atomicAdd(&gloc[o + 3], x.w);
            }
        }
    }
    __syncthreads();
    if (tid < 128) atomicAdd(&gsum[tid], gloc[tid]);
}

// ---------------------------------------------------------------------------
// K4: prob3_sum via bf16 MFMA, A-stationary: block owns a 128-node tile (LDS),
// loops over all 8 p-tiles; wt (256KB) stays L2-hot on every XCD.
// ---------------------------------------------------------------------------
__global__ __launch_bounds__(256) void prob3_mfma(const unsigned short* __restrict__ hb,
                                                  const unsigned short* __restrict__ wt,
                                                  const float* __restrict__ bias,
                                                  float* __restrict__ out, int N) {
    __shared__ unsigned short Ash[128 * 136];
    __shared__ unsigned short Bsh[128 * 136];
    int tid = threadIdx.x;
    int n0 = blockIdx.x * 128;

    {   // stage A once
        int c = tid & 15;
        int r0 = tid >> 4;
        for (int it = 0; it < 8; ++it) {
            int row = r0 + it * 16;
            int v = n0 + row;
            uint4 av = make_uint4(0u, 0u, 0u, 0u);
            if (v < N) av = *(const uint4*)(hb + (size_t)v * H + c * 8);
            *(uint4*)(Ash + row * 136 + c * 8) = av;
        }
    }

    int lane = tid & 63, wid = tid >> 6;
    int wy = wid >> 1, wx = wid & 1;
    int lrow = lane & 15, quad = lane >> 4;
    float lsum = 0.f;

    for (int pt = 0; pt < 8; ++pt) {
        __syncthreads();   // protect Bsh from previous iter's readers (and A after stage)
        {   // stage B tile: rows p0..p0+127 of wt
            int c = tid & 15;
            int r0 = tid >> 4;
            for (int it = 0; it < 8; ++it) {
                int row = r0 + it * 16;
                uint4 bv = *(const uint4*)(wt + (size_t)(pt * 128 + row) * H + c * 8);
                *(uint4*)(Bsh + row * 136 + c * 8) = bv;
            }
        }
        __syncthreads();

        f32x4 acc[4][4];
#pragma unroll
        for (int tm = 0; tm < 4; ++tm)
#pragma unroll
            for (int tn = 0; tn < 4; ++tn)
                acc[tm][tn] = (f32x4){0.f, 0.f, 0.f, 0.f};

        const unsigned short* Abase = Ash + (wy * 64 + lrow) * 136 + quad * 8;
        const unsigned short* Bbase = Bsh + (wx * 64 + lrow) * 136 + quad * 8;
#pragma unroll
        for (int ks = 0; ks < 4; ++ks) {
            bf16x8 a[4], b[4];
#pragma unroll
            for (int t = 0; t < 4; ++t) {
                a[t] = *(const bf16x8*)(Abase + t * 16 * 136 + ks * 32);
                b[t] = *(const bf16x8*)(Bbase + t * 16 * 136 + ks * 32);
            }
#pragma unroll
            for (int tm = 0; tm < 4; ++tm)
#pragma unroll
                for (int tn = 0; tn < 4; ++tn)
                    acc[tm][tn] = __builtin_amdgcn_mfma_f32_16x16x32_bf16(a[tm], b[tn], acc[tm][tn], 0, 0, 0);
        }

#pragma unroll
        for (int tn = 0; tn < 4; ++tn) {
            int p = pt * 128 + wx * 64 + tn * 16 + lrow;
            if (p < PNUM) {
                float bv = bias[p];
#pragma unroll
                for (int tm = 0; tm < 4; ++tm) {
                    int nb = n0 + wy * 64 + tm * 16 + quad * 4;
#pragma unroll
                    for (int r = 0; r < 4; ++r) {
                        if (nb + r < N) lsum += fsig(acc[tm][tn][r] + bv);
                    }
                }
            }
        }
    }
    lsum = wave_reduce(lsum);
    if (lane == 0) atomicAdd(out + 5, lsum);
}

// ---------------------------------------------------------------------------
// K5: per-bucket agg[dst] += pred[src] in LDS, fused out_cost reduction.
// ---------------------------------------------------------------------------
__global__ __launch_bounds__(256) void agg_outcost(
        const uint2* __restrict__ buck, const int* __restrict__ cursor,
        const float* __restrict__ pred, const float* __restrict__ sc,
        float* __restrict__ out, int N) {
    __shared__ float agg[BNODES];
    int tid = threadIdx.x;
    int bkt = blockIdx.x;
    for (int i = tid; i < BNODES; i += 256) agg[i] = 0.0f;
    __syncthreads();
    int cnt = cursor[bkt];
    if (cnt > BCAP) cnt = BCAP;
    if (cnt < 0) cnt = 0;
    const uint2* bp = buck + (size_t)bkt * BCAP;
    for (int i = tid; i < cnt; i += 256) {
        uint2 pl = bp[i];
        int s = pl.x & 0x3FFFF;
        int local = (pl.x >> 18) & 0xFF;
        atomicAdd(&agg[local], pred[s]);
    }
    __syncthreads();
    int base = bkt * BNODES;
    float v = 0.f;
    if (tid < BNODES && base + tid < N) {
        float d = agg[tid] - 1.0f;
        v = d * d * sc[base + tid];
    }
    v = wave_reduce(v);
    if ((tid & 63) == 0) atomicAdd(out + 4, v);
}

// K7: row sums rs[i], col sums cs[j] of pm = pred[:M*M]
__global__ void rowcol_kernel(const float* __restrict__ pred, float* __restrict__ rs,
                              float* __restrict__ cs) {
    int i = blockIdx.x;
    int j = threadIdx.x;
    float p = (j < MNUM) ? pred[i * MNUM + j] : 0.0f;
    if (j < MNUM) atomicAdd(&cs[j], p);
    float s = wave_reduce(p);
    if ((j & 63) == 0) atomicAdd(&rs[i], s);
}

// K8: ce and loss2
__global__ void losses_kernel(const float* __restrict__ pred, const float* __restrict__ gt,
                              const float* __restrict__ rs, const float* __restrict__ cs,
                              float* __restrict__ out) {
    int idx = blockIdx.x * 256 + threadIdx.x;
    float ce = 0.f, l2 = 0.f;
    if (idx < MNUM * MNUM) {
        int i = idx / MNUM, j = idx - i * MNUM;
        float p = pred[idx];
        ce = -gt[idx] * __log2f(p);
        l2 = p * (rs[i] + cs[j] - 2.0f * p);
    }
    ce = wave_reduce(ce);
    l2 = wave_reduce(l2);
    if ((threadIdx.x & 63) == 0) { atomicAdd(out + 3, ce); atomicAdd(out + 2, l2); }
}

// K9: sumone = sum (rs-1)^2 + (cs-1)^2
__global__ void sumone_kernel(const float* __restrict__ rs, const float* __restrict__ cs,
                              float* __restrict__ out) {
    int j = threadIdx.x;
    float v = 0.f;
    if (j < MNUM) {
        float a = rs[j] - 1.0f, b = cs[j] - 1.0f;
        v = a * a + b * b;
    }
    v = wave_reduce(v);
    if ((j & 63) == 0) atomicAdd(out + 1, v);
}

// K10: pred_obj = mean(h) @ fc3_w + fc3_b
__global__ void final_kernel(const float* __restrict__ gsum, const float* __restrict__ fc3_w,
                             const float* __restrict__ fc3_b, float* __restrict__ out, int N) {
    int t = threadIdx.x;  // 64 threads
    float invN = 1.0f / (float)N;
    float v = gsum[t] * invN * fc3_w[t] + gsum[t + 64] * invN * fc3_w[t + 64];
    v = wave_reduce(v);
    if (t == 0) out[0] = v + fc3_b[0];
}

extern "C" void kernel_launch(void* const* d_in, const int* in_sizes, int n_in,
                              void* d_out, int out_size, void* d_ws, size_t ws_size,
                              hipStream_t stream) {
    const float* ntc   = (const float*)d_in[0];
    const float* norm  = (const float*)d_in[1];
    const float* sc    = (const float*)d_in[2];
    const float* gt    = (const float*)d_in[3];
    const float* fc_w  = (const float*)d_in[4];
    const float* fc_b  = (const float*)d_in[5];
    const float* w_nt  = (const float*)d_in[6];
    const float* w_rel = (const float*)d_in[7];
    const float* fc2_w = (const float*)d_in[8];
    const float* fc2_b = (const float*)d_in[9];
    const float* fc3_w = (const float*)d_in[10];
    const float* fc3_b = (const float*)d_in[11];
    const float* fl3_w = (const float*)d_in[12];
    const float* fl3_b = (const float*)d_in[13];
    const int* node_type = (const int*)d_in[14];
    const int* src   = (const int*)d_in[15];
    const int* dst   = (const int*)d_in[16];
    const int* etype = (const int*)d_in[17];
    int N = in_sizes[2];
    int E = in_sizes[1];
    int nbuck = (N + BNODES - 1) / BNODES;   // 250

    // ---- workspace layout (float offsets) ----
    // C:      0      .. 6144
    // G:      6144   .. 6912
    // wt:     6912   .. 72448   (1024*128 bf16 = 131072 shorts = 65536 floats!)
    // gsum:   72448  .. 72576
    // rs:     72576  .. 72832
    // cs:     72832  .. 73088
    // cursor: 73088  .. 73344
    // pred:   73344  .. 73344+N
    // hb:     +N     .. +N+64N  (N*128 bf16)
    // buck:   after  (nbuck*BCAP*2 floats)
    float* ws   = (float*)d_ws;
    float* C    = ws;
    float* G    = ws + 6144;
    unsigned short* wt = (unsigned short*)(ws + 6912);
    float* gsum = ws + 72448;
    float* rs   = ws + 72576;
    float* cs   = ws + 72832;
    int*  cursor = (int*)(ws + 73088);
    float* pred = ws + 73344;
    unsigned short* hb = (unsigned short*)(pred + N);
    uint2* buck = (uint2*)(hb + (size_t)N * H);
    float* out  = (float*)d_out;

    hipMemsetAsync(d_out, 0, 6 * sizeof(float), stream);
    // zero gsum, rs, cs, cursor (contiguous): 896 words
    hipMemsetAsync(gsum, 0, 896 * sizeof(float), stream);

    precompute_G<<<2, 128, 0, stream>>>(fc_w, fc_b, w_nt, G);
    precompute_C2<<<16, 128, 0, stream>>>(G, w_rel, C);
    wt_kernel<<<1024, 128, 0, stream>>>(fl3_w, wt);
    partition_kernel<<<(E + 1023) / 1024, 1024, 0, stream>>>(src, dst, etype, norm,
                                                             node_type, cursor, buck, E);
    bucket_node<<<nbuck, 256, 0, stream>>>(buck, cursor, ntc, C, fc2_w, fc2_b,
                                           hb, pred, gsum, N);
    prob3_mfma<<<(N + 127) / 128, 256, 0, stream>>>(hb, wt, fl3_b, out, N);
    agg_outcost<<<nbuck, 256, 0, stream>>>(buck, cursor, pred, sc, out, N);
    rowcol_kernel<<<MNUM, 256, 0, stream>>>(pred, rs, cs);
    losses_kernel<<<(MNUM * MNUM + 255) / 256, 256, 0, stream>>>(pred, gt, rs, cs, out);
    sumone_kernel<<<1, 256, 0, stream>>>(rs, cs, out);
    final_kernel<<<1, 64, 0, stream>>>(gsum, fc3_w, fc3_b, out, N);
}

// Round 6
// 335.464 us; speedup vs baseline: 3.7441x; 1.0072x over previous
//
#include <hip/hip_runtime.h>

#define H 128
#define RNUM 8
#define TNUM 2
#define PNUM 1000
#define MNUM 223
#define BNODES 200          // nodes per dst-bucket
#define BCAP 7168           // payload capacity per bucket (mean 6400, +9.6 sigma)

typedef __attribute__((ext_vector_type(8))) short bf16x8;
typedef __attribute__((ext_vector_type(4))) float f32x4;

__device__ __forceinline__ float fsig(float z) {
    return 1.0f / (1.0f + __expf(-z));
}
// fast sigmoid: v_rcp_f32 (~1ulp) instead of full-precision divide
__device__ __forceinline__ float fsig_fast(float z) {
    return __builtin_amdgcn_rcpf(1.0f + __expf(-z));
}

__device__ __forceinline__ float wave_reduce(float v) {
#pragma unroll
    for (int off = 32; off > 0; off >>= 1) v += __shfl_down(v, off, 64);
    return v;
}

__device__ __forceinline__ unsigned short f2bf(float f) {
    unsigned int u = __float_as_uint(f);
    u += 0x7fffu + ((u >> 16) & 1u);   // RNE
    return (unsigned short)(u >> 16);
}

// ---------------------------------------------------------------------------
// K1: fused G+C precompute. Block tr = t*8+r (16 blocks, 128 threads).
// G[c][i] = sum_j coef[c][j]*w_nt[t][j][i] (redundant per-t, trivial), then
// C[(tr*3+c)*128+o] = sum_i G[c][i]*w_rel[r][i][o].
// ---------------------------------------------------------------------------
__global__ void precompute_CG(const float* __restrict__ fc_w, const float* __restrict__ fc_b,
                              const float* __restrict__ w_nt, const float* __restrict__ w_rel,
                              float* __restrict__ C) {
    __shared__ float G[3][H];
    int tr = blockIdx.x;
    int t = tr >> 3, r = tr & 7;
    int i = threadIdx.x;
    float a0 = 0.f, a1 = 0.f, a2 = 0.f;
#pragma unroll 8
    for (int j = 0; j < H; ++j) {
        float w = w_nt[((size_t)t * H + j) * H + i];
        a0 += fc_w[j] * w;
        a1 += fc_w[H + j] * w;
        a2 += fc_b[j] * w;
    }
    G[0][i] = a0; G[1][i] = a1; G[2][i] = a2;
    __syncthreads();
    float c0 = 0.f, c1 = 0.f, c2 = 0.f;
#pragma unroll 8
    for (int k = 0; k < H; ++k) {
        float w = w_rel[((size_t)r * H + k) * H + i];
        c0 += G[0][k] * w;
        c1 += G[1][k] * w;
        c2 += G[2][k] * w;
    }
    C[((size_t)tr * 3 + 0) * H + i] = c0;
    C[((size_t)tr * 3 + 1) * H + i] = c1;
    C[((size_t)tr * 3 + 2) * H + i] = c2;
}

// ---------------------------------------------------------------------------
// K1c: wt[p][k] = bf16(fl3_w[k][p]) (p zero-padded to 1024); biasws[p] padded
// with -1e4 so sigmoid of pad columns is exactly 0.
// ---------------------------------------------------------------------------
__global__ void wt_kernel(const float* __restrict__ w, const float* __restrict__ fl3_b,
                          unsigned short* __restrict__ wt, float* __restrict__ biasws) {
    int p = blockIdx.x;   // 0..1023
    int k = threadIdx.x;  // 0..127
    float v = (p < PNUM) ? w[(size_t)k * PNUM + p] : 0.0f;
    wt[(size_t)p * H + k] = f2bf(v);
    if (k == 0) biasws[p] = (p < PNUM) ? fl3_b[p] : -1.0e4f;
}

// ---------------------------------------------------------------------------
// K2: partition edges into dst-range buckets. Payload 8B:
//   .x = src | (local<<18) | (r<<26) | (t<<29)   .y = bits(norm)
// ---------------------------------------------------------------------------
__global__ __launch_bounds__(1024) void partition_kernel(
        const int* __restrict__ src, const int* __restrict__ dst,
        const int* __restrict__ etype, const float* __restrict__ norm,
        const int* __restrict__ node_type, int* __restrict__ cursor,
        uint2* __restrict__ buck, int E) {
    __shared__ int lh[256];
    __shared__ int gb[256];
    int tid = threadIdx.x;
    if (tid < 256) lh[tid] = 0;
    __syncthreads();
    int e = blockIdx.x * 1024 + tid;
    int b = 0, rank = 0;
    uint2 pl;
    bool act = (e < E);
    if (act) {
        int s = src[e];
        int d = dst[e];
        int r = etype[e];
        float nm = norm[e];
        int t = node_type[s];
        b = d / BNODES;
        int local = d - b * BNODES;
        pl.x = (unsigned)s | ((unsigned)local << 18) | ((unsigned)r << 26) | ((unsigned)t << 29);
        pl.y = __float_as_uint(nm);
        rank = atomicAdd(&lh[b], 1);
    }
    __syncthreads();
    if (tid < 256 && lh[tid] > 0) {
        int g = atomicAdd(&cursor[tid], lh[tid]);
        gb[tid] = (g < 0) ? 0 : (g > BCAP ? BCAP : g);   // harden vs corruption
    }
    __syncthreads();
    if (act) {
        int pos = gb[b] + rank;
        if (pos < BCAP) buck[(size_t)b * BCAP + pos] = pl;
    }
}

// ---------------------------------------------------------------------------
// K3: per-bucket: replay edges -> S[200][49] in LDS (LDS atomics), then
// h = relu(S@C) for the bucket's 200 nodes; write hb (bf16), pred, gsum.
// ---------------------------------------------------------------------------
__global__ __launch_bounds__(256) void bucket_node(
        const uint2* __restrict__ buck, const int* __restrict__ cursor,
        const float* __restrict__ ntc, const float* __restrict__ C,
        const float* __restrict__ fc2_w, const float* __restrict__ fc2_b,
        unsigned short* __restrict__ hb, float* __restrict__ pred,
        float* __restrict__ gsum, int N) {
    __shared__ float S[224 * 49];    // 43.9KB
    __shared__ float Csh[48 * 128];  // 24.6KB
    __shared__ float gloc[128];
    int tid = threadIdx.x;
    int bkt = blockIdx.x;
    for (int i = tid; i < 224 * 49; i += 256) S[i] = 0.0f;
    for (int i = tid; i < 48 * 128; i += 256) Csh[i] = C[i];
    if (tid < 128) gloc[tid] = 0.0f;
    __syncthreads();

    int cnt = cursor[bkt];
    if (cnt > BCAP) cnt = BCAP;
    if (cnt < 0) cnt = 0;
    const uint2* bp = buck + (size_t)bkt * BCAP;
    for (int i = tid; i < cnt; i += 256) {
        uint2 pl = bp[i];
        int s = pl.x & 0x3FFFF;
        int local = (pl.x >> 18) & 0xFF;
        int r = (pl.x >> 26) & 7;
        int t = (pl.x >> 29) & 1;
        float nm = __uint_as_float(pl.y);
        float2 c = ((const float2*)ntc)[s];
        float* p = &S[local * 49 + (t * 8 + r) * 3];
        atomicAdd(p, nm * c.x);
        atomicAdd(p + 1, nm * c.y);
        atomicAdd(p + 2, nm);
    }
    __syncthreads();

    int base = bkt * BNODES;
    int sub = tid & 7, vl = tid >> 3;
    const float4* w4 = (const float4*)fc2_w;
    for (int iter = 0; iter < 7; ++iter) {
        int ln = iter * 32 + vl;
        int v = base + ln;
        bool act = (ln < BNODES) && (v < N);
        float4 hv[4];
#pragma unroll
        for (int q = 0; q < 4; ++q) hv[q] = make_float4(0.f, 0.f, 0.f, 0.f);
        const float* Srow = S + ln * 49;
#pragma unroll 4
        for (int k = 0; k < 48; ++k) {
            float sv = Srow[k];
            const float4* Cr = (const float4*)(Csh + k * 128);
#pragma unroll
            for (int q = 0; q < 4; ++q) {
                float4 c = Cr[q * 8 + sub];
                hv[q].x += sv * c.x; hv[q].y += sv * c.y;
                hv[q].z += sv * c.z; hv[q].w += sv * c.w;
            }
        }
#pragma unroll
        for (int q = 0; q < 4; ++q) {
            hv[q].x = fmaxf(hv[q].x, 0.f); hv[q].y = fmaxf(hv[q].y, 0.f);
            hv[q].z = fmaxf(hv[q].z, 0.f); hv[q].w = fmaxf(hv[q].w, 0.f);
        }
        float pd = 0.f;
        if (act) {
            unsigned short* hrow = hb + (size_t)v * H;
#pragma unroll
            for (int q = 0; q < 4; ++q) {
                unsigned int u0 = ((unsigned int)f2bf(hv[q].y) << 16) | f2bf(hv[q].x);
                unsigned int u1 = ((unsigned int)f2bf(hv[q].w) << 16) | f2bf(hv[q].z);
                *(uint2*)(hrow + q * 32 + sub * 4) = make_uint2(u0, u1);
                float4 w = w4[q * 8 + sub];
                pd += hv[q].x * w.x + hv[q].y * w.y + hv[q].z * w.z + hv[q].w * w.w;
            }
        }
#pragma unroll
        for (int off = 4; off > 0; off >>= 1) pd += __shfl_down(pd, off, 8);
        if (sub == 0 && act) {
            float z = pd + fc2_b[0];
            pred[v] = fminf(fmaxf(fsig(z), 1e-7f), 1e10f);
        }
#pragma unroll
        for (int q = 0; q < 4; ++q) {
            float4 x = act ? hv[q] : make_float4(0.f, 0.f, 0.f, 0.f);
#pragma unroll
            for (int d = 8; d < 64; d <<= 1) {
                x.x += __shfl_down(x.x, d, 64); x.y += __shfl_down(x.y, d, 64);
                x.z += __shfl_down(x.z, d, 64); x.w += __shfl_down(x.w, d, 64);
            }
            if ((tid & 63) < 8) {
                int o = q * 32 + sub * 4;
                atomicAdd(&gloc[o], x.x); atomicAdd(&gloc[o + 1], x.y);
                atomicAdd(&gloc[o + 2], x.z); atomicAdd(&gloc[o + 3], x.w);
            }
        }
    }
    __syncthreads();
    if (tid < 128) atomicAdd(&gsum[tid], gloc[tid]);
}

// ---------------------------------------------------------------------------
// K4: prob3 via bf16 MFMA, maskless. Grid (nb128, 2); block = 128-row n-tile
// x 4 p-tiles. A-frags live in registers (coalesced global loads, no Ash);
// Bsh only -> 34.8KB LDS -> 4 blocks/CU. hb padded to padN rows (zeroed);
// bias padded with -1e4 (sigmoid->0); pad-row contribution subtracted in
// final_kernel. Epilogue has ZERO per-element branches.
// ---------------------------------------------------------------------------
__global__ __launch_bounds__(256, 2) void prob3_mfma(const unsigned short* __restrict__ hb,
                                                     const unsigned short* __restrict__ wt,
                                                     const float* __restrict__ biasws,
                                                     float* __restrict__ out) {
    __shared__ unsigned short Bsh[128 * 136];
    int tid = threadIdx.x;
    int n0 = blockIdx.x * 128;
    int pt0 = blockIdx.y * 4;

    int lane = tid & 63, wid = tid >> 6;
    int wy = wid >> 1, wx = wid & 1;
    int lrow = lane & 15, quad = lane >> 4;

    // A fragments: persistent in registers. Per (tm,ks) instruction the 64
    // lanes read 16 rows x 64B contiguous -> fully coalesced.
    bf16x8 a[4][4];
#pragma unroll
    for (int tm = 0; tm < 4; ++tm) {
        const unsigned short* arow = hb + (size_t)(n0 + wy * 64 + tm * 16 + lrow) * H + quad * 8;
#pragma unroll
        for (int ks = 0; ks < 4; ++ks)
            a[tm][ks] = *(const bf16x8*)(arow + ks * 32);
    }

    float lsum = 0.f;
    for (int pi = 0; pi < 4; ++pi) {
        int pt = pt0 + pi;
        __syncthreads();
        {   // stage B tile (always valid: wt is 1024 rows)
            int c = tid & 15;
            int r0 = tid >> 4;
#pragma unroll
            for (int it = 0; it < 8; ++it) {
                int row = r0 + it * 16;
                uint4 bv = *(const uint4*)(wt + (size_t)(pt * 128 + row) * H + c * 8);
                *(uint4*)(Bsh + row * 136 + c * 8) = bv;
            }
        }
        __syncthreads();

        f32x4 acc[4][4];
#pragma unroll
        for (int tm = 0; tm < 4; ++tm)
#pragma unroll
            for (int tn = 0; tn < 4; ++tn)
                acc[tm][tn] = (f32x4){0.f, 0.f, 0.f, 0.f};

        const unsigned short* Bbase = Bsh + (wx * 64 + lrow) * 136 + quad * 8;
#pragma unroll
        for (int ks = 0; ks < 4; ++ks) {
            bf16x8 b[4];
#pragma unroll
            for (int tn = 0; tn < 4; ++tn)
                b[tn] = *(const bf16x8*)(Bbase + tn * 16 * 136 + ks * 32);
#pragma unroll
            for (int tm = 0; tm < 4; ++tm)
#pragma unroll
                for (int tn = 0; tn < 4; ++tn)
                    acc[tm][tn] = __builtin_amdgcn_mfma_f32_16x16x32_bf16(a[tm][ks], b[tn], acc[tm][tn], 0, 0, 0);
        }

        // maskless epilogue
#pragma unroll
        for (int tn = 0; tn < 4; ++tn) {
            float bv = biasws[pt * 128 + wx * 64 + tn * 16 + lrow];
#pragma unroll
            for (int tm = 0; tm < 4; ++tm) {
#pragma unroll
                for (int r = 0; r < 4; ++r)
                    lsum += fsig_fast(acc[tm][tn][r] + bv);
            }
        }
    }
    lsum = wave_reduce(lsum);
    if (lane == 0) atomicAdd(out + 5, lsum);
}

// ---------------------------------------------------------------------------
// K5: per-bucket agg[dst] += pred[src] in LDS, fused out_cost reduction.
// ---------------------------------------------------------------------------
__global__ __launch_bounds__(256) void agg_outcost(
        const uint2* __restrict__ buck, const int* __restrict__ cursor,
        const float* __restrict__ pred, const float* __restrict__ sc,
        float* __restrict__ out, int N) {
    __shared__ float agg[BNODES];
    int tid = threadIdx.x;
    int bkt = blockIdx.x;
    for (int i = tid; i < BNODES; i += 256) agg[i] = 0.0f;
    __syncthreads();
    int cnt = cursor[bkt];
    if (cnt > BCAP) cnt = BCAP;
    if (cnt < 0) cnt = 0;
    const uint2* bp = buck + (size_t)bkt * BCAP;
    for (int i = tid; i < cnt; i += 256) {
        uint2 pl = bp[i];
        int s = pl.x & 0x3FFFF;
        int local = (pl.x >> 18) & 0xFF;
        atomicAdd(&agg[local], pred[s]);
    }
    __syncthreads();
    int base = bkt * BNODES;
    float v = 0.f;
    if (tid < BNODES && base + tid < N) {
        float d = agg[tid] - 1.0f;
        v = d * d * sc[base + tid];
    }
    v = wave_reduce(v);
    if ((tid & 63) == 0) atomicAdd(out + 4, v);
}

// K7: row sums rs[i], col sums cs[j] of pm = pred[:M*M]
__global__ void rowcol_kernel(const float* __restrict__ pred, float* __restrict__ rs,
                              float* __restrict__ cs) {
    int i = blockIdx.x;
    int j = threadIdx.x;
    float p = (j < MNUM) ? pred[i * MNUM + j] : 0.0f;
    if (j < MNUM) atomicAdd(&cs[j], p);
    float s = wave_reduce(p);
    if ((j & 63) == 0) atomicAdd(&rs[i], s);
}

// K8: ce and loss2
__global__ void losses_kernel(const float* __restrict__ pred, const float* __restrict__ gt,
                              const float* __restrict__ rs, const float* __restrict__ cs,
                              float* __restrict__ out) {
    int idx = blockIdx.x * 256 + threadIdx.x;
    float ce = 0.f, l2 = 0.f;
    if (idx < MNUM * MNUM) {
        int i = idx / MNUM, j = idx - i * MNUM;
        float p = pred[idx];
        ce = -gt[idx] * __log2f(p);
        l2 = p * (rs[i] + cs[j] - 2.0f * p);
    }
    ce = wave_reduce(ce);
    l2 = wave_reduce(l2);
    if ((threadIdx.x & 63) == 0) { atomicAdd(out + 3, ce); atomicAdd(out + 2, l2); }
}

// K9: sumone = sum (rs-1)^2 + (cs-1)^2
__global__ void sumone_kernel(const float* __restrict__ rs, const float* __restrict__ cs,
                              float* __restrict__ out) {
    int j = threadIdx.x;
    float v = 0.f;
    if (j < MNUM) {
        float a = rs[j] - 1.0f, b = cs[j] - 1.0f;
        v = a * a + b * b;
    }
    v = wave_reduce(v);
    if ((j & 63) == 0) atomicAdd(out + 1, v);
}

// K10: pred_obj = mean(h)@fc3_w + fc3_b; also subtract prob3 pad-row term:
// padrows * sum_p fsig_fast(fl3_b[p])  (pad rows of hb are zero -> acc==0).
__global__ void final_kernel(const float* __restrict__ gsum, const float* __restrict__ fc3_w,
                             const float* __restrict__ fc3_b, const float* __restrict__ fl3_b,
                             float* __restrict__ out, int N, int padrows) {
    int t = threadIdx.x;  // 64 threads
    float invN = 1.0f / (float)N;
    float v = gsum[t] * invN * fc3_w[t] + gsum[t + 64] * invN * fc3_w[t + 64];
    v = wave_reduce(v);
    float s = 0.f;
    for (int p = t; p < PNUM; p += 64) s += fsig_fast(fl3_b[p]);
    s = wave_reduce(s);
    if (t == 0) {
        out[0] = v + fc3_b[0];
        atomicAdd(out + 5, -(float)padrows * s);
    }
}

extern "C" void kernel_launch(void* const* d_in, const int* in_sizes, int n_in,
                              void* d_out, int out_size, void* d_ws, size_t ws_size,
                              hipStream_t stream) {
    const float* ntc   = (const float*)d_in[0];
    const float* norm  = (const float*)d_in[1];
    const float* sc    = (const float*)d_in[2];
    const float* gt    = (const float*)d_in[3];
    const float* fc_w  = (const float*)d_in[4];
    const float* fc_b  = (const float*)d_in[5];
    const float* w_nt  = (const float*)d_in[6];
    const float* w_rel = (const float*)d_in[7];
    const float* fc2_w = (const float*)d_in[8];
    const float* fc2_b = (const float*)d_in[9];
    const float* fc3_w = (const float*)d_in[10];
    const float* fc3_b = (const float*)d_in[11];
    const float* fl3_w = (const float*)d_in[12];
    const float* fl3_b = (const float*)d_in[13];
    const int* node_type = (const int*)d_in[14];
    const int* src   = (const int*)d_in[15];
    const int* dst   = (const int*)d_in[16];
    const int* etype = (const int*)d_in[17];
    int N = in_sizes[2];
    int E = in_sizes[1];
    int nbuck = (N + BNODES - 1) / BNODES;   // 250
    int nb128 = (N + 127) / 128;             // 391
    int padN  = nb128 * 128;                 // 50048

    // ---- workspace layout (float offsets) ----
    // C:      0      .. 6144
    // wt:     6144   .. 71680   (1024*128 bf16 = 65536 floats)
    // biasws: 71680  .. 72704   (1024)
    // gsum:   72704  .. 72832
    // rs:     72832  .. 73088
    // cs:     73088  .. 73344
    // cursor: 73344  .. 73600
    // pred:   73600  .. +N
    // hb:     +N     .. +N + padN*64   (padN*128 bf16)
    // buck:   after  (nbuck*BCAP*2 floats)
    float* ws   = (float*)d_ws;
    float* C    = ws;
    unsigned short* wt = (unsigned short*)(ws + 6144);
    float* biasws = ws + 71680;
    float* gsum = ws + 72704;
    float* rs   = ws + 72832;
    float* cs   = ws + 73088;
    int*  cursor = (int*)(ws + 73344);
    float* pred = ws + 73600;
    unsigned short* hb = (unsigned short*)(pred + N);
    uint2* buck = (uint2*)(hb + (size_t)padN * H);
    float* out  = (float*)d_out;

    hipMemsetAsync(d_out, 0, 6 * sizeof(float), stream);
    // zero gsum, rs, cs, cursor (contiguous): 896 words
    hipMemsetAsync(gsum, 0, 896 * sizeof(float), stream);
    // zero hb pad rows (read unconditionally by prob3)
    hipMemsetAsync(hb + (size_t)N * H, 0, (size_t)(padN - N) * H * sizeof(unsigned short), stream);

    wt_kernel<<<1024, 128, 0, stream>>>(fl3_w, fl3_b, wt, biasws);
    precompute_CG<<<16, 128, 0, stream>>>(fc_w, fc_b, w_nt, w_rel, C);
    partition_kernel<<<(E + 1023) / 1024, 1024, 0, stream>>>(src, dst, etype, norm,
                                                             node_type, cursor, buck, E);
    bucket_node<<<nbuck, 256, 0, stream>>>(buck, cursor, ntc, C, fc2_w, fc2_b,
                                           hb, pred, gsum, N);
    prob3_mfma<<<dim3(nb128, 2), 256, 0, stream>>>(hb, wt, biasws, out);
    agg_outcost<<<nbuck, 256, 0, stream>>>(buck, cursor, pred, sc, out, N);
    rowcol_kernel<<<MNUM, 256, 0, stream>>>(pred, rs, cs);
    losses_kernel<<<(MNUM * MNUM + 255) / 256, 256, 0, stream>>>(pred, gt, rs, cs, out);
    sumone_kernel<<<1, 256, 0, stream>>>(rs, cs, out);
    final_kernel<<<1, 64, 0, stream>>>(gsum, fc3_w, fc3_b, fl3_b, out, N, padN - N);
}

// Round 7
// 326.764 us; speedup vs baseline: 3.8438x; 1.0266x over previous
//
#include <hip/hip_runtime.h>

#define H 128
#define RNUM 8
#define TNUM 2
#define PNUM 1000
#define MNUM 223
#define BNODES 200          // nodes per dst-bucket
#define BCAP 7168           // payload capacity per bucket (mean 6400, +9.6 sigma)

typedef __attribute__((ext_vector_type(8))) short bf16x8;
typedef __attribute__((ext_vector_type(4))) float f32x4;

__device__ __forceinline__ float fsig(float z) {
    return 1.0f / (1.0f + __expf(-z));
}
// fast sigmoid: v_rcp_f32 (~1ulp) instead of full-precision divide
__device__ __forceinline__ float fsig_fast(float z) {
    return __builtin_amdgcn_rcpf(1.0f + __expf(-z));
}

__device__ __forceinline__ float wave_reduce(float v) {
#pragma unroll
    for (int off = 32; off > 0; off >>= 1) v += __shfl_down(v, off, 64);
    return v;
}

__device__ __forceinline__ unsigned short f2bf(float f) {
    unsigned int u = __float_as_uint(f);
    u += 0x7fffu + ((u >> 16) & 1u);   // RNE
    return (unsigned short)(u >> 16);
}

// ---------------------------------------------------------------------------
// K1: fused G+C precompute. Block tr = t*8+r (16 blocks, 128 threads).
// ---------------------------------------------------------------------------
__global__ void precompute_CG(const float* __restrict__ fc_w, const float* __restrict__ fc_b,
                              const float* __restrict__ w_nt, const float* __restrict__ w_rel,
                              float* __restrict__ C) {
    __shared__ float G[3][H];
    int tr = blockIdx.x;
    int t = tr >> 3, r = tr & 7;
    int i = threadIdx.x;
    float a0 = 0.f, a1 = 0.f, a2 = 0.f;
#pragma unroll 8
    for (int j = 0; j < H; ++j) {
        float w = w_nt[((size_t)t * H + j) * H + i];
        a0 += fc_w[j] * w;
        a1 += fc_w[H + j] * w;
        a2 += fc_b[j] * w;
    }
    G[0][i] = a0; G[1][i] = a1; G[2][i] = a2;
    __syncthreads();
    float c0 = 0.f, c1 = 0.f, c2 = 0.f;
#pragma unroll 8
    for (int k = 0; k < H; ++k) {
        float w = w_rel[((size_t)r * H + k) * H + i];
        c0 += G[0][k] * w;
        c1 += G[1][k] * w;
        c2 += G[2][k] * w;
    }
    C[((size_t)tr * 3 + 0) * H + i] = c0;
    C[((size_t)tr * 3 + 1) * H + i] = c1;
    C[((size_t)tr * 3 + 2) * H + i] = c2;
}

// ---------------------------------------------------------------------------
// K1c: wt[p][k] = bf16(fl3_w[k][p]) (p zero-padded to 1024); biasws[p] padded
// with -1e4 so sigmoid of pad columns is exactly 0.
// ---------------------------------------------------------------------------
__global__ void wt_kernel(const float* __restrict__ w, const float* __restrict__ fl3_b,
                          unsigned short* __restrict__ wt, float* __restrict__ biasws) {
    int p = blockIdx.x;   // 0..1023
    int k = threadIdx.x;  // 0..127
    float v = (p < PNUM) ? w[(size_t)k * PNUM + p] : 0.0f;
    wt[(size_t)p * H + k] = f2bf(v);
    if (k == 0) biasws[p] = (p < PNUM) ? fl3_b[p] : -1.0e4f;
}

// ---------------------------------------------------------------------------
// K2: partition edges into dst-range buckets. Payload 8B:
//   .x = src | (local<<18) | (r<<26) | (t<<29)   .y = bits(norm)
// ---------------------------------------------------------------------------
__global__ __launch_bounds__(1024) void partition_kernel(
        const int* __restrict__ src, const int* __restrict__ dst,
        const int* __restrict__ etype, const float* __restrict__ norm,
        const int* __restrict__ node_type, int* __restrict__ cursor,
        uint2* __restrict__ buck, int E) {
    __shared__ int lh[256];
    __shared__ int gb[256];
    int tid = threadIdx.x;
    if (tid < 256) lh[tid] = 0;
    __syncthreads();
    int e = blockIdx.x * 1024 + tid;
    int b = 0, rank = 0;
    uint2 pl;
    bool act = (e < E);
    if (act) {
        int s = src[e];
        int d = dst[e];
        int r = etype[e];
        float nm = norm[e];
        int t = node_type[s];
        b = d / BNODES;
        int local = d - b * BNODES;
        pl.x = (unsigned)s | ((unsigned)local << 18) | ((unsigned)r << 26) | ((unsigned)t << 29);
        pl.y = __float_as_uint(nm);
        rank = atomicAdd(&lh[b], 1);
    }
    __syncthreads();
    if (tid < 256 && lh[tid] > 0) {
        int g = atomicAdd(&cursor[tid], lh[tid]);
        gb[tid] = (g < 0) ? 0 : (g > BCAP ? BCAP : g);   // harden vs corruption
    }
    __syncthreads();
    if (act) {
        int pos = gb[b] + rank;
        if (pos < BCAP) buck[(size_t)b * BCAP + pos] = pl;
    }
}

// ---------------------------------------------------------------------------
// K3: per-bucket: replay edges -> S[200][49] in LDS (LDS atomics), then
// h = relu(S@C). 512 threads (8 waves: replay latency hiding), node phase
// loop-swapped: k outer, 4 node-passes accumulated in registers so the C
// fragment is read once per k (4x less LDS traffic than node-outer form).
// ---------------------------------------------------------------------------
__global__ __launch_bounds__(512) void bucket_node(
        const uint2* __restrict__ buck, const int* __restrict__ cursor,
        const float* __restrict__ ntc, const float* __restrict__ C,
        const float* __restrict__ fc2_w, const float* __restrict__ fc2_b,
        unsigned short* __restrict__ hb, float* __restrict__ pred,
        float* __restrict__ gsum, int N) {
    __shared__ float S[256 * 49];    // 50.2KB (256 rows: 4 passes x 64 nodes)
    __shared__ float Csh[48 * 128];  // 24.6KB
    __shared__ float gloc[128];
    int tid = threadIdx.x;
    int bkt = blockIdx.x;
    for (int i = tid; i < 256 * 49; i += 512) S[i] = 0.0f;
    for (int i = tid; i < 48 * 128; i += 512) Csh[i] = C[i];
    if (tid < 128) gloc[tid] = 0.0f;
    __syncthreads();

    int cnt = cursor[bkt];
    if (cnt > BCAP) cnt = BCAP;
    if (cnt < 0) cnt = 0;
    const uint2* bp = buck + (size_t)bkt * BCAP;
    for (int i = tid; i < cnt; i += 512) {
        uint2 pl = bp[i];
        int s = pl.x & 0x3FFFF;
        int local = (pl.x >> 18) & 0xFF;
        int r = (pl.x >> 26) & 7;
        int t = (pl.x >> 29) & 1;
        float nm = __uint_as_float(pl.y);
        float2 c = ((const float2*)ntc)[s];
        float* p = &S[local * 49 + (t * 8 + r) * 3];
        atomicAdd(p, nm * c.x);
        atomicAdd(p + 1, nm * c.y);
        atomicAdd(p + 2, nm);
    }
    __syncthreads();

    int base = bkt * BNODES;
    int sub = tid & 7, vl = tid >> 3;   // vl in 0..63
    // 4 passes x 4 quads of float4 accumulators, all live
    float4 hv[4][4];
#pragma unroll
    for (int ps = 0; ps < 4; ++ps)
#pragma unroll
        for (int q = 0; q < 4; ++q) hv[ps][q] = make_float4(0.f, 0.f, 0.f, 0.f);

#pragma unroll 2
    for (int k = 0; k < 48; ++k) {
        float4 c[4];
        const float4* Cr = (const float4*)(Csh + k * 128);
#pragma unroll
        for (int q = 0; q < 4; ++q) c[q] = Cr[q * 8 + sub];
#pragma unroll
        for (int ps = 0; ps < 4; ++ps) {
            float sv = S[(ps * 64 + vl) * 49 + k];
#pragma unroll
            for (int q = 0; q < 4; ++q) {
                hv[ps][q].x += sv * c[q].x; hv[ps][q].y += sv * c[q].y;
                hv[ps][q].z += sv * c[q].z; hv[ps][q].w += sv * c[q].w;
            }
        }
    }

    const float4* w4 = (const float4*)fc2_w;
#pragma unroll
    for (int ps = 0; ps < 4; ++ps) {
        int ln = ps * 64 + vl;
        int v = base + ln;
        bool act = (ln < BNODES) && (v < N);
#pragma unroll
        for (int q = 0; q < 4; ++q) {
            hv[ps][q].x = fmaxf(hv[ps][q].x, 0.f); hv[ps][q].y = fmaxf(hv[ps][q].y, 0.f);
            hv[ps][q].z = fmaxf(hv[ps][q].z, 0.f); hv[ps][q].w = fmaxf(hv[ps][q].w, 0.f);
        }
        float pd = 0.f;
        if (act) {
            unsigned short* hrow = hb + (size_t)v * H;
#pragma unroll
            for (int q = 0; q < 4; ++q) {
                unsigned int u0 = ((unsigned int)f2bf(hv[ps][q].y) << 16) | f2bf(hv[ps][q].x);
                unsigned int u1 = ((unsigned int)f2bf(hv[ps][q].w) << 16) | f2bf(hv[ps][q].z);
                *(uint2*)(hrow + q * 32 + sub * 4) = make_uint2(u0, u1);
                float4 w = w4[q * 8 + sub];
                pd += hv[ps][q].x * w.x + hv[ps][q].y * w.y + hv[ps][q].z * w.z + hv[ps][q].w * w.w;
            }
        }
#pragma unroll
        for (int off = 4; off > 0; off >>= 1) pd += __shfl_down(pd, off, 8);
        if (sub == 0 && act) {
            float z = pd + fc2_b[0];
            pred[v] = fminf(fmaxf(fsig(z), 1e-7f), 1e10f);
        }
#pragma unroll
        for (int q = 0; q < 4; ++q) {
            float4 x = act ? hv[ps][q] : make_float4(0.f, 0.f, 0.f, 0.f);
#pragma unroll
            for (int d = 8; d < 64; d <<= 1) {
                x.x += __shfl_down(x.x, d, 64); x.y += __shfl_down(x.y, d, 64);
                x.z += __shfl_down(x.z, d, 64); x.w += __shfl_down(x.w, d, 64);
            }
            if ((tid & 63) < 8) {
                int o = q * 32 + sub * 4;
                atomicAdd(&gloc[o], x.x); atomicAdd(&gloc[o + 1], x.y);
                atomicAdd(&gloc[o + 2], x.z); atomicAdd(&gloc[o + 3], x.w);
            }
        }
    }
    __syncthreads();
    if (tid < 128) atomicAdd(&gsum[tid], gloc[tid]);
}

// ---------------------------------------------------------------------------
// K4: prob3 via bf16 MFMA, maskless (see R5 notes). A-frags in registers,
// Bsh only; pad rows/cols corrected analytically in the tail kernel.
// ---------------------------------------------------------------------------
__global__ __launch_bounds__(256, 2) void prob3_mfma(const unsigned short* __restrict__ hb,
                                                     const unsigned short* __restrict__ wt,
                                                     const float* __restrict__ biasws,
                                                     float* __restrict__ out) {
    __shared__ unsigned short Bsh[128 * 136];
    int tid = threadIdx.x;
    int n0 = blockIdx.x * 128;
    int pt0 = blockIdx.y * 4;

    int lane = tid & 63, wid = tid >> 6;
    int wy = wid >> 1, wx = wid & 1;
    int lrow = lane & 15, quad = lane >> 4;

    bf16x8 a[4][4];
#pragma unroll
    for (int tm = 0; tm < 4; ++tm) {
        const unsigned short* arow = hb + (size_t)(n0 + wy * 64 + tm * 16 + lrow) * H + quad * 8;
#pragma unroll
        for (int ks = 0; ks < 4; ++ks)
            a[tm][ks] = *(const bf16x8*)(arow + ks * 32);
    }

    float lsum = 0.f;
    for (int pi = 0; pi < 4; ++pi) {
        int pt = pt0 + pi;
        __syncthreads();
        {
            int c = tid & 15;
            int r0 = tid >> 4;
#pragma unroll
            for (int it = 0; it < 8; ++it) {
                int row = r0 + it * 16;
                uint4 bv = *(const uint4*)(wt + (size_t)(pt * 128 + row) * H + c * 8);
                *(uint4*)(Bsh + row * 136 + c * 8) = bv;
            }
        }
        __syncthreads();

        f32x4 acc[4][4];
#pragma unroll
        for (int tm = 0; tm < 4; ++tm)
#pragma unroll
            for (int tn = 0; tn < 4; ++tn)
                acc[tm][tn] = (f32x4){0.f, 0.f, 0.f, 0.f};

        const unsigned short* Bbase = Bsh + (wx * 64 + lrow) * 136 + quad * 8;
#pragma unroll
        for (int ks = 0; ks < 4; ++ks) {
            bf16x8 b[4];
#pragma unroll
            for (int tn = 0; tn < 4; ++tn)
                b[tn] = *(const bf16x8*)(Bbase + tn * 16 * 136 + ks * 32);
#pragma unroll
            for (int tm = 0; tm < 4; ++tm)
#pragma unroll
                for (int tn = 0; tn < 4; ++tn)
                    acc[tm][tn] = __builtin_amdgcn_mfma_f32_16x16x32_bf16(a[tm][ks], b[tn], acc[tm][tn], 0, 0, 0);
        }

#pragma unroll
        for (int tn = 0; tn < 4; ++tn) {
            float bv = biasws[pt * 128 + wx * 64 + tn * 16 + lrow];
#pragma unroll
            for (int tm = 0; tm < 4; ++tm) {
#pragma unroll
                for (int r = 0; r < 4; ++r)
                    lsum += fsig_fast(acc[tm][tn][r] + bv);
            }
        }
    }
    lsum = wave_reduce(lsum);
    if (lane == 0) atomicAdd(out + 5, lsum);
}

// ---------------------------------------------------------------------------
// K5: per-bucket agg[dst] += pred[src] in LDS, fused out_cost reduction.
// 1024 threads for replay latency hiding.
// ---------------------------------------------------------------------------
__global__ __launch_bounds__(1024) void agg_outcost(
        const uint2* __restrict__ buck, const int* __restrict__ cursor,
        const float* __restrict__ pred, const float* __restrict__ sc,
        float* __restrict__ out, int N) {
    __shared__ float agg[BNODES];
    int tid = threadIdx.x;
    int bkt = blockIdx.x;
    if (tid < BNODES) agg[tid] = 0.0f;
    __syncthreads();
    int cnt = cursor[bkt];
    if (cnt > BCAP) cnt = BCAP;
    if (cnt < 0) cnt = 0;
    const uint2* bp = buck + (size_t)bkt * BCAP;
    for (int i = tid; i < cnt; i += 1024) {
        uint2 pl = bp[i];
        int s = pl.x & 0x3FFFF;
        int local = (pl.x >> 18) & 0xFF;
        atomicAdd(&agg[local], pred[s]);
    }
    __syncthreads();
    int base = bkt * BNODES;
    float v = 0.f;
    if (tid < BNODES && base + tid < N) {
        float d = agg[tid] - 1.0f;
        v = d * d * sc[base + tid];
    }
    v = wave_reduce(v);
    if ((tid & 63) == 0 && tid < BNODES + 63) atomicAdd(out + 4, v);
}

// K7: row sums rs[i], col sums cs[j] of pm = pred[:M*M]
__global__ void rowcol_kernel(const float* __restrict__ pred, float* __restrict__ rs,
                              float* __restrict__ cs) {
    int i = blockIdx.x;
    int j = threadIdx.x;
    float p = (j < MNUM) ? pred[i * MNUM + j] : 0.0f;
    if (j < MNUM) atomicAdd(&cs[j], p);
    float s = wave_reduce(p);
    if ((j & 63) == 0) atomicAdd(&rs[i], s);
}

// K8 (fused tail): blocks 0..194 -> ce & loss2; block 195 -> sumone + final
// (pred_obj from gsum, prob3 pad-row correction).
__global__ void tail_kernel(const float* __restrict__ pred, const float* __restrict__ gt,
                            const float* __restrict__ rs, const float* __restrict__ cs,
                            const float* __restrict__ gsum, const float* __restrict__ fc3_w,
                            const float* __restrict__ fc3_b, const float* __restrict__ fl3_b,
                            float* __restrict__ out, int N, int padrows) {
    int blk = blockIdx.x;
    int tid = threadIdx.x;
    if (blk < 195) {
        int idx = blk * 256 + tid;
        float ce = 0.f, l2 = 0.f;
        if (idx < MNUM * MNUM) {
            int i = idx / MNUM, j = idx - i * MNUM;
            float p = pred[idx];
            ce = -gt[idx] * __log2f(p);
            l2 = p * (rs[i] + cs[j] - 2.0f * p);
        }
        ce = wave_reduce(ce);
        l2 = wave_reduce(l2);
        if ((tid & 63) == 0) { atomicAdd(out + 3, ce); atomicAdd(out + 2, l2); }
    } else {
        // sumone
        float v = 0.f;
        if (tid < MNUM) {
            float a = rs[tid] - 1.0f, b = cs[tid] - 1.0f;
            v = a * a + b * b;
        }
        v = wave_reduce(v);
        if ((tid & 63) == 0) atomicAdd(out + 1, v);
        // final (first wave only)
        if (tid < 64) {
            float invN = 1.0f / (float)N;
            float pv = gsum[tid] * invN * fc3_w[tid] + gsum[tid + 64] * invN * fc3_w[tid + 64];
            pv = wave_reduce(pv);
            float s = 0.f;
            for (int p = tid; p < PNUM; p += 64) s += fsig_fast(fl3_b[p]);
            s = wave_reduce(s);
            if (tid == 0) {
                out[0] = pv + fc3_b[0];
                atomicAdd(out + 5, -(float)padrows * s);
            }
        }
    }
}

extern "C" void kernel_launch(void* const* d_in, const int* in_sizes, int n_in,
                              void* d_out, int out_size, void* d_ws, size_t ws_size,
                              hipStream_t stream) {
    const float* ntc   = (const float*)d_in[0];
    const float* norm  = (const float*)d_in[1];
    const float* sc    = (const float*)d_in[2];
    const float* gt    = (const float*)d_in[3];
    const float* fc_w  = (const float*)d_in[4];
    const float* fc_b  = (const float*)d_in[5];
    const float* w_nt  = (const float*)d_in[6];
    const float* w_rel = (const float*)d_in[7];
    const float* fc2_w = (const float*)d_in[8];
    const float* fc2_b = (const float*)d_in[9];
    const float* fc3_w = (const float*)d_in[10];
    const float* fc3_b = (const float*)d_in[11];
    const float* fl3_w = (const float*)d_in[12];
    const float* fl3_b = (const float*)d_in[13];
    const int* node_type = (const int*)d_in[14];
    const int* src   = (const int*)d_in[15];
    const int* dst   = (const int*)d_in[16];
    const int* etype = (const int*)d_in[17];
    int N = in_sizes[2];
    int E = in_sizes[1];
    int nbuck = (N + BNODES - 1) / BNODES;   // 250
    int nb128 = (N + 127) / 128;             // 391
    int padN  = nb128 * 128;                 // 50048

    // ---- workspace layout (float offsets) ----
    // C:      0      .. 6144
    // wt:     6144   .. 71680   (1024*128 bf16 = 65536 floats)
    // biasws: 71680  .. 72704   (1024)
    // gsum:   72704  .. 72832
    // rs:     72832  .. 73088
    // cs:     73088  .. 73344
    // cursor: 73344  .. 73600
    // pred:   73600  .. +N
    // hb:     +N     .. +N + padN*64   (padN*128 bf16)
    // buck:   after  (nbuck*BCAP*2 floats)
    float* ws   = (float*)d_ws;
    float* C    = ws;
    unsigned short* wt = (unsigned short*)(ws + 6144);
    float* biasws = ws + 71680;
    float* gsum = ws + 72704;
    float* rs   = ws + 72832;
    float* cs   = ws + 73088;
    int*  cursor = (int*)(ws + 73344);
    float* pred = ws + 73600;
    unsigned short* hb = (unsigned short*)(pred + N);
    uint2* buck = (uint2*)(hb + (size_t)padN * H);
    float* out  = (float*)d_out;

    hipMemsetAsync(d_out, 0, 6 * sizeof(float), stream);
    hipMemsetAsync(gsum, 0, 896 * sizeof(float), stream);   // gsum,rs,cs,cursor
    hipMemsetAsync(hb + (size_t)N * H, 0, (size_t)(padN - N) * H * sizeof(unsigned short), stream);

    wt_kernel<<<1024, 128, 0, stream>>>(fl3_w, fl3_b, wt, biasws);
    precompute_CG<<<16, 128, 0, stream>>>(fc_w, fc_b, w_nt, w_rel, C);
    partition_kernel<<<(E + 1023) / 1024, 1024, 0, stream>>>(src, dst, etype, norm,
                                                             node_type, cursor, buck, E);
    bucket_node<<<nbuck, 512, 0, stream>>>(buck, cursor, ntc, C, fc2_w, fc2_b,
                                           hb, pred, gsum, N);
    prob3_mfma<<<dim3(nb128, 2), 256, 0, stream>>>(hb, wt, biasws, out);
    agg_outcost<<<nbuck, 1024, 0, stream>>>(buck, cursor, pred, sc, out, N);
    rowcol_kernel<<<MNUM, 256, 0, stream>>>(pred, rs, cs);
    tail_kernel<<<196, 256, 0, stream>>>(pred, gt, rs, cs, gsum, fc3_w, fc3_b, fl3_b,
                                         out, N, padN - N);
}

// Round 8
// 267.964 us; speedup vs baseline: 4.6872x; 1.2194x over previous
//
#include <hip/hip_runtime.h>

#define H 128
#define RNUM 8
#define TNUM 2
#define PNUM 1000
#define MNUM 223
#define BNODES 200          // nodes per dst-bucket
#define BCAP 7168           // payload capacity per bucket (mean 6400, +9.6 sigma)

typedef __attribute__((ext_vector_type(8))) short bf16x8;
typedef __attribute__((ext_vector_type(4))) float f32x4;

__device__ __forceinline__ float fsig(float z) {
    return 1.0f / (1.0f + __expf(-z));
}
// fast sigmoid: v_rcp_f32 (~1ulp) instead of full-precision divide
__device__ __forceinline__ float fsig_fast(float z) {
    return __builtin_amdgcn_rcpf(1.0f + __expf(-z));
}

__device__ __forceinline__ float wave_reduce(float v) {
#pragma unroll
    for (int off = 32; off > 0; off >>= 1) v += __shfl_down(v, off, 64);
    return v;
}

__device__ __forceinline__ unsigned short f2bf(float f) {
    unsigned int u = __float_as_uint(f);
    u += 0x7fffu + ((u >> 16) & 1u);   // RNE
    return (unsigned short)(u >> 16);
}

// ---------------------------------------------------------------------------
// K1: fused G+C precompute. Block tr = t*8+r (16 blocks, 128 threads).
// ---------------------------------------------------------------------------
__global__ void precompute_CG(const float* __restrict__ fc_w, const float* __restrict__ fc_b,
                              const float* __restrict__ w_nt, const float* __restrict__ w_rel,
                              float* __restrict__ C) {
    __shared__ float G[3][H];
    int tr = blockIdx.x;
    int t = tr >> 3, r = tr & 7;
    int i = threadIdx.x;
    float a0 = 0.f, a1 = 0.f, a2 = 0.f;
#pragma unroll 8
    for (int j = 0; j < H; ++j) {
        float w = w_nt[((size_t)t * H + j) * H + i];
        a0 += fc_w[j] * w;
        a1 += fc_w[H + j] * w;
        a2 += fc_b[j] * w;
    }
    G[0][i] = a0; G[1][i] = a1; G[2][i] = a2;
    __syncthreads();
    float c0 = 0.f, c1 = 0.f, c2 = 0.f;
#pragma unroll 8
    for (int k = 0; k < H; ++k) {
        float w = w_rel[((size_t)r * H + k) * H + i];
        c0 += G[0][k] * w;
        c1 += G[1][k] * w;
        c2 += G[2][k] * w;
    }
    C[((size_t)tr * 3 + 0) * H + i] = c0;
    C[((size_t)tr * 3 + 1) * H + i] = c1;
    C[((size_t)tr * 3 + 2) * H + i] = c2;
}

// ---------------------------------------------------------------------------
// K1c: wt[p][k] = bf16(fl3_w[k][p]) (p zero-padded to 1024); biasws[p] padded
// with -1e4 so sigmoid of pad columns is exactly 0.
// ---------------------------------------------------------------------------
__global__ void wt_kernel(const float* __restrict__ w, const float* __restrict__ fl3_b,
                          unsigned short* __restrict__ wt, float* __restrict__ biasws) {
    int p = blockIdx.x;   // 0..1023
    int k = threadIdx.x;  // 0..127
    float v = (p < PNUM) ? w[(size_t)k * PNUM + p] : 0.0f;
    wt[(size_t)p * H + k] = f2bf(v);
    if (k == 0) biasws[p] = (p < PNUM) ? fl3_b[p] : -1.0e4f;
}

// ---------------------------------------------------------------------------
// K2: partition edges into dst-range buckets. Payload 8B:
//   .x = src | (local<<18) | (r<<26) | (t<<29)   .y = bits(norm)
// ---------------------------------------------------------------------------
__global__ __launch_bounds__(1024) void partition_kernel(
        const int* __restrict__ src, const int* __restrict__ dst,
        const int* __restrict__ etype, const float* __restrict__ norm,
        const int* __restrict__ node_type, int* __restrict__ cursor,
        uint2* __restrict__ buck, int E) {
    __shared__ int lh[256];
    __shared__ int gb[256];
    int tid = threadIdx.x;
    if (tid < 256) lh[tid] = 0;
    __syncthreads();
    int e = blockIdx.x * 1024 + tid;
    int b = 0, rank = 0;
    uint2 pl;
    bool act = (e < E);
    if (act) {
        int s = src[e];
        int d = dst[e];
        int r = etype[e];
        float nm = norm[e];
        int t = node_type[s];
        b = d / BNODES;
        int local = d - b * BNODES;
        pl.x = (unsigned)s | ((unsigned)local << 18) | ((unsigned)r << 26) | ((unsigned)t << 29);
        pl.y = __float_as_uint(nm);
        rank = atomicAdd(&lh[b], 1);
    }
    __syncthreads();
    if (tid < 256 && lh[tid] > 0) {
        int g = atomicAdd(&cursor[tid], lh[tid]);
        gb[tid] = (g < 0) ? 0 : (g > BCAP ? BCAP : g);   // harden vs corruption
    }
    __syncthreads();
    if (act) {
        int pos = gb[b] + rank;
        if (pos < BCAP) buck[(size_t)b * BCAP + pos] = pl;
    }
}

// ---------------------------------------------------------------------------
// K3: per-bucket: replay edges -> S[200][49] in LDS (LDS atomics), then
// h = relu(S@C). 512 threads, k-outer node phase (see R6 notes).
// ---------------------------------------------------------------------------
__global__ __launch_bounds__(512) void bucket_node(
        const uint2* __restrict__ buck, const int* __restrict__ cursor,
        const float* __restrict__ ntc, const float* __restrict__ C,
        const float* __restrict__ fc2_w, const float* __restrict__ fc2_b,
        unsigned short* __restrict__ hb, float* __restrict__ pred,
        float* __restrict__ gsum, int N) {
    __shared__ float S[256 * 49];    // 50.2KB
    __shared__ float Csh[48 * 128];  // 24.6KB
    __shared__ float gloc[128];
    int tid = threadIdx.x;
    int bkt = blockIdx.x;
    for (int i = tid; i < 256 * 49; i += 512) S[i] = 0.0f;
    for (int i = tid; i < 48 * 128; i += 512) Csh[i] = C[i];
    if (tid < 128) gloc[tid] = 0.0f;
    __syncthreads();

    int cnt = cursor[bkt];
    if (cnt > BCAP) cnt = BCAP;
    if (cnt < 0) cnt = 0;
    const uint2* bp = buck + (size_t)bkt * BCAP;
    for (int i = tid; i < cnt; i += 512) {
        uint2 pl = bp[i];
        int s = pl.x & 0x3FFFF;
        int local = (pl.x >> 18) & 0xFF;
        int r = (pl.x >> 26) & 7;
        int t = (pl.x >> 29) & 1;
        float nm = __uint_as_float(pl.y);
        float2 c = ((const float2*)ntc)[s];
        float* p = &S[local * 49 + (t * 8 + r) * 3];
        atomicAdd(p, nm * c.x);
        atomicAdd(p + 1, nm * c.y);
        atomicAdd(p + 2, nm);
    }
    __syncthreads();

    int base = bkt * BNODES;
    int sub = tid & 7, vl = tid >> 3;   // vl in 0..63
    float4 hv[4][4];
#pragma unroll
    for (int ps = 0; ps < 4; ++ps)
#pragma unroll
        for (int q = 0; q < 4; ++q) hv[ps][q] = make_float4(0.f, 0.f, 0.f, 0.f);

#pragma unroll 2
    for (int k = 0; k < 48; ++k) {
        float4 c[4];
        const float4* Cr = (const float4*)(Csh + k * 128);
#pragma unroll
        for (int q = 0; q < 4; ++q) c[q] = Cr[q * 8 + sub];
#pragma unroll
        for (int ps = 0; ps < 4; ++ps) {
            float sv = S[(ps * 64 + vl) * 49 + k];
#pragma unroll
            for (int q = 0; q < 4; ++q) {
                hv[ps][q].x += sv * c[q].x; hv[ps][q].y += sv * c[q].y;
                hv[ps][q].z += sv * c[q].z; hv[ps][q].w += sv * c[q].w;
            }
        }
    }

    const float4* w4 = (const float4*)fc2_w;
#pragma unroll
    for (int ps = 0; ps < 4; ++ps) {
        int ln = ps * 64 + vl;
        int v = base + ln;
        bool act = (ln < BNODES) && (v < N);
#pragma unroll
        for (int q = 0; q < 4; ++q) {
            hv[ps][q].x = fmaxf(hv[ps][q].x, 0.f); hv[ps][q].y = fmaxf(hv[ps][q].y, 0.f);
            hv[ps][q].z = fmaxf(hv[ps][q].z, 0.f); hv[ps][q].w = fmaxf(hv[ps][q].w, 0.f);
        }
        float pd = 0.f;
        if (act) {
            unsigned short* hrow = hb + (size_t)v * H;
#pragma unroll
            for (int q = 0; q < 4; ++q) {
                unsigned int u0 = ((unsigned int)f2bf(hv[ps][q].y) << 16) | f2bf(hv[ps][q].x);
                unsigned int u1 = ((unsigned int)f2bf(hv[ps][q].w) << 16) | f2bf(hv[ps][q].z);
                *(uint2*)(hrow + q * 32 + sub * 4) = make_uint2(u0, u1);
                float4 w = w4[q * 8 + sub];
                pd += hv[ps][q].x * w.x + hv[ps][q].y * w.y + hv[ps][q].z * w.z + hv[ps][q].w * w.w;
            }
        }
#pragma unroll
        for (int off = 4; off > 0; off >>= 1) pd += __shfl_down(pd, off, 8);
        if (sub == 0 && act) {
            float z = pd + fc2_b[0];
            pred[v] = fminf(fmaxf(fsig(z), 1e-7f), 1e10f);
        }
#pragma unroll
        for (int q = 0; q < 4; ++q) {
            float4 x = act ? hv[ps][q] : make_float4(0.f, 0.f, 0.f, 0.f);
#pragma unroll
            for (int d = 8; d < 64; d <<= 1) {
                x.x += __shfl_down(x.x, d, 64); x.y += __shfl_down(x.y, d, 64);
                x.z += __shfl_down(x.z, d, 64); x.w += __shfl_down(x.w, d, 64);
            }
            if ((tid & 63) < 8) {
                int o = q * 32 + sub * 4;
                atomicAdd(&gloc[o], x.x); atomicAdd(&gloc[o + 1], x.y);
                atomicAdd(&gloc[o + 2], x.z); atomicAdd(&gloc[o + 3], x.w);
            }
        }
    }
    __syncthreads();
    if (tid < 128) atomicAdd(&gsum[tid], gloc[tid]);
}

// ---------------------------------------------------------------------------
// K4: prob3 via bf16 MFMA, maskless. NO global atomics: 4 wave partials are
// LDS-reduced and plain-stored to psum[block] (782 entries); tail sums.
// ---------------------------------------------------------------------------
__global__ __launch_bounds__(256, 2) void prob3_mfma(const unsigned short* __restrict__ hb,
                                                     const unsigned short* __restrict__ wt,
                                                     const float* __restrict__ biasws,
                                                     float* __restrict__ psum, int nb128) {
    __shared__ unsigned short Bsh[128 * 136];
    __shared__ float wsum[4];
    int tid = threadIdx.x;
    int n0 = blockIdx.x * 128;
    int pt0 = blockIdx.y * 4;

    int lane = tid & 63, wid = tid >> 6;
    int wy = wid >> 1, wx = wid & 1;
    int lrow = lane & 15, quad = lane >> 4;

    bf16x8 a[4][4];
#pragma unroll
    for (int tm = 0; tm < 4; ++tm) {
        const unsigned short* arow = hb + (size_t)(n0 + wy * 64 + tm * 16 + lrow) * H + quad * 8;
#pragma unroll
        for (int ks = 0; ks < 4; ++ks)
            a[tm][ks] = *(const bf16x8*)(arow + ks * 32);
    }

    float lsum = 0.f;
    for (int pi = 0; pi < 4; ++pi) {
        int pt = pt0 + pi;
        __syncthreads();
        {
            int c = tid & 15;
            int r0 = tid >> 4;
#pragma unroll
            for (int it = 0; it < 8; ++it) {
                int row = r0 + it * 16;
                uint4 bv = *(const uint4*)(wt + (size_t)(pt * 128 + row) * H + c * 8);
                *(uint4*)(Bsh + row * 136 + c * 8) = bv;
            }
        }
        __syncthreads();

        f32x4 acc[4][4];
#pragma unroll
        for (int tm = 0; tm < 4; ++tm)
#pragma unroll
            for (int tn = 0; tn < 4; ++tn)
                acc[tm][tn] = (f32x4){0.f, 0.f, 0.f, 0.f};

        const unsigned short* Bbase = Bsh + (wx * 64 + lrow) * 136 + quad * 8;
#pragma unroll
        for (int ks = 0; ks < 4; ++ks) {
            bf16x8 b[4];
#pragma unroll
            for (int tn = 0; tn < 4; ++tn)
                b[tn] = *(const bf16x8*)(Bbase + tn * 16 * 136 + ks * 32);
#pragma unroll
            for (int tm = 0; tm < 4; ++tm)
#pragma unroll
                for (int tn = 0; tn < 4; ++tn)
                    acc[tm][tn] = __builtin_amdgcn_mfma_f32_16x16x32_bf16(a[tm][ks], b[tn], acc[tm][tn], 0, 0, 0);
        }

#pragma unroll
        for (int tn = 0; tn < 4; ++tn) {
            float bv = biasws[pt * 128 + wx * 64 + tn * 16 + lrow];
#pragma unroll
            for (int tm = 0; tm < 4; ++tm) {
#pragma unroll
                for (int r = 0; r < 4; ++r)
                    lsum += fsig_fast(acc[tm][tn][r] + bv);
            }
        }
    }
    lsum = wave_reduce(lsum);
    if (lane == 0) wsum[wid] = lsum;
    __syncthreads();
    if (tid == 0)
        psum[blockIdx.y * nb128 + blockIdx.x] = wsum[0] + wsum[1] + wsum[2] + wsum[3];
}

// ---------------------------------------------------------------------------
// K5: per-bucket agg[dst] += pred[src] in LDS, fused out_cost reduction.
// 1024 threads; 16 wave partials LDS-reduced -> ONE atomic per block.
// ---------------------------------------------------------------------------
__global__ __launch_bounds__(1024) void agg_outcost(
        const uint2* __restrict__ buck, const int* __restrict__ cursor,
        const float* __restrict__ pred, const float* __restrict__ sc,
        float* __restrict__ out, int N) {
    __shared__ float agg[BNODES];
    __shared__ float wsum[16];
    int tid = threadIdx.x;
    int bkt = blockIdx.x;
    if (tid < BNODES) agg[tid] = 0.0f;
    __syncthreads();
    int cnt = cursor[bkt];
    if (cnt > BCAP) cnt = BCAP;
    if (cnt < 0) cnt = 0;
    const uint2* bp = buck + (size_t)bkt * BCAP;
    for (int i = tid; i < cnt; i += 1024) {
        uint2 pl = bp[i];
        int s = pl.x & 0x3FFFF;
        int local = (pl.x >> 18) & 0xFF;
        atomicAdd(&agg[local], pred[s]);
    }
    __syncthreads();
    int base = bkt * BNODES;
    float v = 0.f;
    if (tid < BNODES && base + tid < N) {
        float d = agg[tid] - 1.0f;
        v = d * d * sc[base + tid];
    }
    v = wave_reduce(v);
    if ((tid & 63) == 0) wsum[tid >> 6] = v;
    __syncthreads();
    if (tid == 0) {
        float s = 0.f;
#pragma unroll
        for (int w = 0; w < 16; ++w) s += wsum[w];
        atomicAdd(out + 4, s);
    }
}

// K7: row sums rs[i], col sums cs[j] of pm = pred[:M*M]
__global__ void rowcol_kernel(const float* __restrict__ pred, float* __restrict__ rs,
                              float* __restrict__ cs) {
    int i = blockIdx.x;
    int j = threadIdx.x;
    float p = (j < MNUM) ? pred[i * MNUM + j] : 0.0f;
    if (j < MNUM) atomicAdd(&cs[j], p);
    float s = wave_reduce(p);
    if ((j & 63) == 0) atomicAdd(&rs[i], s);
}

// K8 (fused tail): blocks 0..194 -> ce & loss2 (1 atomic/block each);
// block 195 -> sumone (plain store), pred_obj (plain store), prob3 total
// from psum + pad-row correction (plain store).
__global__ void tail_kernel(const float* __restrict__ pred, const float* __restrict__ gt,
                            const float* __restrict__ rs, const float* __restrict__ cs,
                            const float* __restrict__ gsum, const float* __restrict__ fc3_w,
                            const float* __restrict__ fc3_b, const float* __restrict__ fl3_b,
                            const float* __restrict__ psum, int npsum,
                            float* __restrict__ out, int N, int padrows) {
    __shared__ float red[8];
    int blk = blockIdx.x;
    int tid = threadIdx.x;
    int wid = tid >> 6;
    if (blk < 195) {
        int idx = blk * 256 + tid;
        float ce = 0.f, l2 = 0.f;
        if (idx < MNUM * MNUM) {
            int i = idx / MNUM, j = idx - i * MNUM;
            float p = pred[idx];
            ce = -gt[idx] * __log2f(p);
            l2 = p * (rs[i] + cs[j] - 2.0f * p);
        }
        ce = wave_reduce(ce);
        l2 = wave_reduce(l2);
        if ((tid & 63) == 0) { red[wid] = ce; red[4 + wid] = l2; }
        __syncthreads();
        if (tid == 0) {
            atomicAdd(out + 3, red[0] + red[1] + red[2] + red[3]);
            atomicAdd(out + 2, red[4] + red[5] + red[6] + red[7]);
        }
    } else {
        // sumone (single writer -> plain store)
        float v = 0.f;
        if (tid < MNUM) {
            float a = rs[tid] - 1.0f, b = cs[tid] - 1.0f;
            v = a * a + b * b;
        }
        v = wave_reduce(v);
        if ((tid & 63) == 0) red[wid] = v;
        __syncthreads();
        if (tid == 0) out[1] = red[0] + red[1] + red[2] + red[3];
        __syncthreads();
        // prob3_sum = sum(psum) - padrows * sum_p sigmoid(fl3_b[p])
        float ps = 0.f;
        for (int i = tid; i < npsum; i += 256) ps += psum[i];
        float ss = 0.f;
        for (int p = tid; p < PNUM; p += 256) ss += fsig_fast(fl3_b[p]);
        float comb = ps - (float)padrows * ss;
        comb = wave_reduce(comb);
        if ((tid & 63) == 0) red[4 + wid] = comb;
        __syncthreads();
        if (tid == 0) out[5] = red[4] + red[5] + red[6] + red[7];
        // pred_obj (threads 0..127, 2 waves)
        float pv = 0.f;
        if (tid < 128) pv = gsum[tid] * (1.0f / (float)N) * fc3_w[tid];
        pv = wave_reduce(pv);
        if ((tid & 63) == 0 && tid < 128) red[wid] = pv;
        __syncthreads();
        if (tid == 0) out[0] = red[0] + red[1] + fc3_b[0];
    }
}

extern "C" void kernel_launch(void* const* d_in, const int* in_sizes, int n_in,
                              void* d_out, int out_size, void* d_ws, size_t ws_size,
                              hipStream_t stream) {
    const float* ntc   = (const float*)d_in[0];
    const float* norm  = (const float*)d_in[1];
    const float* sc    = (const float*)d_in[2];
    const float* gt    = (const float*)d_in[3];
    const float* fc_w  = (const float*)d_in[4];
    const float* fc_b  = (const float*)d_in[5];
    const float* w_nt  = (const float*)d_in[6];
    const float* w_rel = (const float*)d_in[7];
    const float* fc2_w = (const float*)d_in[8];
    const float* fc2_b = (const float*)d_in[9];
    const float* fc3_w = (const float*)d_in[10];
    const float* fc3_b = (const float*)d_in[11];
    const float* fl3_w = (const float*)d_in[12];
    const float* fl3_b = (const float*)d_in[13];
    const int* node_type = (const int*)d_in[14];
    const int* src   = (const int*)d_in[15];
    const int* dst   = (const int*)d_in[16];
    const int* etype = (const int*)d_in[17];
    int N = in_sizes[2];
    int E = in_sizes[1];
    int nbuck = (N + BNODES - 1) / BNODES;   // 250
    int nb128 = (N + 127) / 128;             // 391
    int padN  = nb128 * 128;                 // 50048
    int npsum = nb128 * 2;                   // 782

    // ---- workspace layout (float offsets) ----
    // C:      0      .. 6144
    // wt:     6144   .. 71680   (1024*128 bf16 = 65536 floats)
    // biasws: 71680  .. 72704
    // gsum:   72704  .. 72832
    // rs:     72832  .. 73088
    // cs:     73088  .. 73344
    // cursor: 73344  .. 73600
    // psum:   73600  .. 74624   (1024; 782 used)
    // pred:   74624  .. +N
    // hb:     +N     .. +N + padN*64
    // buck:   after
    float* ws   = (float*)d_ws;
    float* C    = ws;
    unsigned short* wt = (unsigned short*)(ws + 6144);
    float* biasws = ws + 71680;
    float* gsum = ws + 72704;
    float* rs   = ws + 72832;
    float* cs   = ws + 73088;
    int*  cursor = (int*)(ws + 73344);
    float* psum = ws + 73600;
    float* pred = ws + 74624;
    unsigned short* hb = (unsigned short*)(pred + N);
    uint2* buck = (uint2*)(hb + (size_t)padN * H);
    float* out  = (float*)d_out;

    hipMemsetAsync(d_out, 0, 6 * sizeof(float), stream);
    hipMemsetAsync(gsum, 0, 896 * sizeof(float), stream);   // gsum,rs,cs,cursor
    hipMemsetAsync(hb + (size_t)N * H, 0, (size_t)(padN - N) * H * sizeof(unsigned short), stream);

    wt_kernel<<<1024, 128, 0, stream>>>(fl3_w, fl3_b, wt, biasws);
    precompute_CG<<<16, 128, 0, stream>>>(fc_w, fc_b, w_nt, w_rel, C);
    partition_kernel<<<(E + 1023) / 1024, 1024, 0, stream>>>(src, dst, etype, norm,
                                                             node_type, cursor, buck, E);
    bucket_node<<<nbuck, 512, 0, stream>>>(buck, cursor, ntc, C, fc2_w, fc2_b,
                                           hb, pred, gsum, N);
    prob3_mfma<<<dim3(nb128, 2), 256, 0, stream>>>(hb, wt, biasws, psum, nb128);
    agg_outcost<<<nbuck, 1024, 0, stream>>>(buck, cursor, pred, sc, out, N);
    rowcol_kernel<<<MNUM, 256, 0, stream>>>(pred, rs, cs);
    tail_kernel<<<196, 256, 0, stream>>>(pred, gt, rs, cs, gsum, fc3_w, fc3_b, fl3_b,
                                         psum, npsum, out, N, padN - N);
}

// Round 9
// 264.567 us; speedup vs baseline: 4.7474x; 1.0128x over previous
//
#include <hip/hip_runtime.h>

#define H 128
#define RNUM 8
#define TNUM 2
#define PNUM 1000
#define MNUM 223
#define BNODES 64           // nodes per dst-bucket (power of 2)
#define NBUCK 782           // padN / 64
#define BCAP 2304           // per-bucket capacity (mean 2048, +5.7 sigma)
#define EPB 8192            // edges per partition block

typedef __attribute__((ext_vector_type(8))) short bf16x8;
typedef __attribute__((ext_vector_type(4))) float f32x4;

__device__ __forceinline__ float fsig(float z) {
    return 1.0f / (1.0f + __expf(-z));
}
__device__ __forceinline__ float fsig_fast(float z) {
    return __builtin_amdgcn_rcpf(1.0f + __expf(-z));
}

__device__ __forceinline__ float wave_reduce(float v) {
#pragma unroll
    for (int off = 32; off > 0; off >>= 1) v += __shfl_down(v, off, 64);
    return v;
}

__device__ __forceinline__ unsigned short f2bf(float f) {
    unsigned int u = __float_as_uint(f);
    u += 0x7fffu + ((u >> 16) & 1u);   // RNE
    return (unsigned short)(u >> 16);
}

// ---------------------------------------------------------------------------
// K1: fused G+C precompute. Block tr = t*8+r (16 blocks, 128 threads).
// ---------------------------------------------------------------------------
__global__ void precompute_CG(const float* __restrict__ fc_w, const float* __restrict__ fc_b,
                              const float* __restrict__ w_nt, const float* __restrict__ w_rel,
                              float* __restrict__ C) {
    __shared__ float G[3][H];
    int tr = blockIdx.x;
    int t = tr >> 3, r = tr & 7;
    int i = threadIdx.x;
    float a0 = 0.f, a1 = 0.f, a2 = 0.f;
#pragma unroll 8
    for (int j = 0; j < H; ++j) {
        float w = w_nt[((size_t)t * H + j) * H + i];
        a0 += fc_w[j] * w;
        a1 += fc_w[H + j] * w;
        a2 += fc_b[j] * w;
    }
    G[0][i] = a0; G[1][i] = a1; G[2][i] = a2;
    __syncthreads();
    float c0 = 0.f, c1 = 0.f, c2 = 0.f;
#pragma unroll 8
    for (int k = 0; k < H; ++k) {
        float w = w_rel[((size_t)r * H + k) * H + i];
        c0 += G[0][k] * w;
        c1 += G[1][k] * w;
        c2 += G[2][k] * w;
    }
    C[((size_t)tr * 3 + 0) * H + i] = c0;
    C[((size_t)tr * 3 + 1) * H + i] = c1;
    C[((size_t)tr * 3 + 2) * H + i] = c2;
}

// ---------------------------------------------------------------------------
// K1c: wt[p][k] = bf16(fl3_w[k][p]) (p zero-padded to 1024); biasws[p] padded
// with -1e4 so sigmoid of pad columns is exactly 0.
// ---------------------------------------------------------------------------
__global__ void wt_kernel(const float* __restrict__ w, const float* __restrict__ fl3_b,
                          unsigned short* __restrict__ wt, float* __restrict__ biasws) {
    int p = blockIdx.x;   // 0..1023
    int k = threadIdx.x;  // 0..127
    float v = (p < PNUM) ? w[(size_t)k * PNUM + p] : 0.0f;
    wt[(size_t)p * H + k] = f2bf(v);
    if (k == 0) biasws[p] = (p < PNUM) ? fl3_b[p] : -1.0e4f;
}

// ---------------------------------------------------------------------------
// K2: partition edges into 64-node dst buckets. 8192 edges/block.
// Payload: .x = src | (local<<18) | (r<<24) | (t<<27); .y = bits(norm)
// ---------------------------------------------------------------------------
__global__ __launch_bounds__(1024) void partition_kernel(
        const int* __restrict__ src, const int* __restrict__ dst,
        const int* __restrict__ etype, const float* __restrict__ norm,
        const int* __restrict__ node_type, int* __restrict__ cursor,
        uint2* __restrict__ buck, int E) {
    __shared__ int lh[NBUCK];
    __shared__ int gb[NBUCK];
    int tid = threadIdx.x;
    for (int i = tid; i < NBUCK; i += 1024) lh[i] = 0;
    __syncthreads();
    int base = blockIdx.x * EPB;
    uint2 pl[8]; int bb[8]; int rk[8];
#pragma unroll
    for (int c = 0; c < 8; ++c) {
        int e = base + c * 1024 + tid;
        bb[c] = -1;
        if (e < E) {
            int s = src[e];
            int d = dst[e];
            int r = etype[e];
            float nm = norm[e];
            int t = node_type[s];
            int b = d >> 6;
            int local = d & 63;
            pl[c].x = (unsigned)s | ((unsigned)local << 18) | ((unsigned)r << 24) | ((unsigned)t << 27);
            pl[c].y = __float_as_uint(nm);
            bb[c] = b;
            rk[c] = atomicAdd(&lh[b], 1);
        }
    }
    __syncthreads();
    for (int i = tid; i < NBUCK; i += 1024) {
        if (lh[i] > 0) {
            int g = atomicAdd(&cursor[i], lh[i]);
            gb[i] = (g < 0) ? 0 : (g > BCAP ? BCAP : g);
        }
    }
    __syncthreads();
#pragma unroll
    for (int c = 0; c < 8; ++c) {
        if (bb[c] >= 0) {
            int pos = gb[bb[c]] + rk[c];
            if (pos < BCAP) buck[(size_t)bb[c] * BCAP + pos] = pl[c];
        }
    }
}

// ---------------------------------------------------------------------------
// K3: per-bucket: replay edges -> S[64][49] in LDS, then h = relu(S@C) in one
// pass (512 thr = 64 nodes x 8 subs). LDS 37.7KB -> 4 blocks/CU, 32 waves/CU.
// gsum partial -> plain store gpart[bkt][128] (no global atomics).
// ---------------------------------------------------------------------------
__global__ __launch_bounds__(512) void bucket_node(
        const uint2* __restrict__ buck, const int* __restrict__ cursor,
        const float* __restrict__ ntc, const float* __restrict__ C,
        const float* __restrict__ fc2_w, const float* __restrict__ fc2_b,
        unsigned short* __restrict__ hb, float* __restrict__ pred,
        float* __restrict__ gpart, int N) {
    __shared__ float S[64 * 49];     // 12.5KB
    __shared__ float Csh[48 * 128];  // 24.6KB
    __shared__ float gloc[128];
    int tid = threadIdx.x;
    int bkt = blockIdx.x;
    for (int i = tid; i < 64 * 49; i += 512) S[i] = 0.0f;
    for (int i = tid; i < 48 * 128; i += 512) Csh[i] = C[i];
    if (tid < 128) gloc[tid] = 0.0f;
    __syncthreads();

    int cnt = cursor[bkt];
    if (cnt > BCAP) cnt = BCAP;
    if (cnt < 0) cnt = 0;
    const uint2* bp = buck + (size_t)bkt * BCAP;
    for (int i = tid; i < cnt; i += 512) {
        uint2 pl = bp[i];
        int s = pl.x & 0x3FFFF;
        int local = (pl.x >> 18) & 63;
        int r = (pl.x >> 24) & 7;
        int t = (pl.x >> 27) & 1;
        float nm = __uint_as_float(pl.y);
        float2 c = ((const float2*)ntc)[s];
        float* p = &S[local * 49 + (t * 8 + r) * 3];
        atomicAdd(p, nm * c.x);
        atomicAdd(p + 1, nm * c.y);
        atomicAdd(p + 2, nm);
    }
    __syncthreads();

    int sub = tid & 7, vl = tid >> 3;   // vl = node 0..63
    int v = bkt * BNODES + vl;
    bool act = (v < N);
    float4 hv[4];
#pragma unroll
    for (int q = 0; q < 4; ++q) hv[q] = make_float4(0.f, 0.f, 0.f, 0.f);

#pragma unroll 4
    for (int k = 0; k < 48; ++k) {
        float sv = S[vl * 49 + k];
        const float4* Cr = (const float4*)(Csh + k * 128);
#pragma unroll
        for (int q = 0; q < 4; ++q) {
            float4 c = Cr[q * 8 + sub];
            hv[q].x += sv * c.x; hv[q].y += sv * c.y;
            hv[q].z += sv * c.z; hv[q].w += sv * c.w;
        }
    }
#pragma unroll
    for (int q = 0; q < 4; ++q) {
        hv[q].x = fmaxf(hv[q].x, 0.f); hv[q].y = fmaxf(hv[q].y, 0.f);
        hv[q].z = fmaxf(hv[q].z, 0.f); hv[q].w = fmaxf(hv[q].w, 0.f);
    }
    float pd = 0.f;
    if (act) {
        unsigned short* hrow = hb + (size_t)v * H;
        const float4* w4 = (const float4*)fc2_w;
#pragma unroll
        for (int q = 0; q < 4; ++q) {
            unsigned int u0 = ((unsigned int)f2bf(hv[q].y) << 16) | f2bf(hv[q].x);
            unsigned int u1 = ((unsigned int)f2bf(hv[q].w) << 16) | f2bf(hv[q].z);
            *(uint2*)(hrow + q * 32 + sub * 4) = make_uint2(u0, u1);
            float4 w = w4[q * 8 + sub];
            pd += hv[q].x * w.x + hv[q].y * w.y + hv[q].z * w.z + hv[q].w * w.w;
        }
    }
#pragma unroll
    for (int off = 4; off > 0; off >>= 1) pd += __shfl_down(pd, off, 8);
    if (sub == 0 && act) {
        float z = pd + fc2_b[0];
        pred[v] = fminf(fmaxf(fsig(z), 1e-7f), 1e10f);
    }
#pragma unroll
    for (int q = 0; q < 4; ++q) {
        float4 x = act ? hv[q] : make_float4(0.f, 0.f, 0.f, 0.f);
#pragma unroll
        for (int d = 8; d < 64; d <<= 1) {
            x.x += __shfl_down(x.x, d, 64); x.y += __shfl_down(x.y, d, 64);
            x.z += __shfl_down(x.z, d, 64); x.w += __shfl_down(x.w, d, 64);
        }
        if ((tid & 63) < 8) {
            int o = q * 32 + sub * 4;
            atomicAdd(&gloc[o], x.x); atomicAdd(&gloc[o + 1], x.y);
            atomicAdd(&gloc[o + 2], x.z); atomicAdd(&gloc[o + 3], x.w);
        }
    }
    __syncthreads();
    if (tid < 128) gpart[(size_t)bkt * 128 + tid] = gloc[tid];
}

// ---------------------------------------------------------------------------
// K4: prob3 via bf16 MFMA, maskless; per-block plain store to psum.
// ---------------------------------------------------------------------------
__global__ __launch_bounds__(256, 2) void prob3_mfma(const unsigned short* __restrict__ hb,
                                                     const unsigned short* __restrict__ wt,
                                                     const float* __restrict__ biasws,
                                                     float* __restrict__ psum, int nb128) {
    __shared__ unsigned short Bsh[128 * 136];
    __shared__ float wsum[4];
    int tid = threadIdx.x;
    int n0 = blockIdx.x * 128;
    int pt0 = blockIdx.y * 4;

    int lane = tid & 63, wid = tid >> 6;
    int wy = wid >> 1, wx = wid & 1;
    int lrow = lane & 15, quad = lane >> 4;

    bf16x8 a[4][4];
#pragma unroll
    for (int tm = 0; tm < 4; ++tm) {
        const unsigned short* arow = hb + (size_t)(n0 + wy * 64 + tm * 16 + lrow) * H + quad * 8;
#pragma unroll
        for (int ks = 0; ks < 4; ++ks)
            a[tm][ks] = *(const bf16x8*)(arow + ks * 32);
    }

    float lsum = 0.f;
    for (int pi = 0; pi < 4; ++pi) {
        int pt = pt0 + pi;
        __syncthreads();
        {
            int c = tid & 15;
            int r0 = tid >> 4;
#pragma unroll
            for (int it = 0; it < 8; ++it) {
                int row = r0 + it * 16;
                uint4 bv = *(const uint4*)(wt + (size_t)(pt * 128 + row) * H + c * 8);
                *(uint4*)(Bsh + row * 136 + c * 8) = bv;
            }
        }
        __syncthreads();

        f32x4 acc[4][4];
#pragma unroll
        for (int tm = 0; tm < 4; ++tm)
#pragma unroll
            for (int tn = 0; tn < 4; ++tn)
                acc[tm][tn] = (f32x4){0.f, 0.f, 0.f, 0.f};

        const unsigned short* Bbase = Bsh + (wx * 64 + lrow) * 136 + quad * 8;
#pragma unroll
        for (int ks = 0; ks < 4; ++ks) {
            bf16x8 b[4];
#pragma unroll
            for (int tn = 0; tn < 4; ++tn)
                b[tn] = *(const bf16x8*)(Bbase + tn * 16 * 136 + ks * 32);
#pragma unroll
            for (int tm = 0; tm < 4; ++tm)
#pragma unroll
                for (int tn = 0; tn < 4; ++tn)
                    acc[tm][tn] = __builtin_amdgcn_mfma_f32_16x16x32_bf16(a[tm][ks], b[tn], acc[tm][tn], 0, 0, 0);
        }

#pragma unroll
        for (int tn = 0; tn < 4; ++tn) {
            float bv = biasws[pt * 128 + wx * 64 + tn * 16 + lrow];
#pragma unroll
            for (int tm = 0; tm < 4; ++tm) {
#pragma unroll
                for (int r = 0; r < 4; ++r)
                    lsum += fsig_fast(acc[tm][tn][r] + bv);
            }
        }
    }
    lsum = wave_reduce(lsum);
    if (lane == 0) wsum[wid] = lsum;
    __syncthreads();
    if (tid == 0)
        psum[blockIdx.y * nb128 + blockIdx.x] = wsum[0] + wsum[1] + wsum[2] + wsum[3];
}

// ---------------------------------------------------------------------------
// K5: per-bucket agg[dst] += pred[src] in LDS; out_cost partial plain-stored.
// ---------------------------------------------------------------------------
__global__ __launch_bounds__(256) void agg_outcost(
        const uint2* __restrict__ buck, const int* __restrict__ cursor,
        const float* __restrict__ pred, const float* __restrict__ sc,
        float* __restrict__ ocpart, int N) {
    __shared__ float agg[BNODES];
    int tid = threadIdx.x;
    int bkt = blockIdx.x;
    if (tid < BNODES) agg[tid] = 0.0f;
    __syncthreads();
    int cnt = cursor[bkt];
    if (cnt > BCAP) cnt = BCAP;
    if (cnt < 0) cnt = 0;
    const uint2* bp = buck + (size_t)bkt * BCAP;
    for (int i = tid; i < cnt; i += 256) {
        uint2 pl = bp[i];
        int s = pl.x & 0x3FFFF;
        int local = (pl.x >> 18) & 63;
        atomicAdd(&agg[local], pred[s]);
    }
    __syncthreads();
    if (tid < 64) {
        float v = 0.f;
        int node = bkt * BNODES + tid;
        if (node < N) {
            float d = agg[tid] - 1.0f;
            v = d * d * sc[node];
        }
        v = wave_reduce(v);
        if (tid == 0) ocpart[bkt] = v;
    }
}

// K6: rs (blocks 0..222) and cs (blocks 223..445), plain stores, no atomics.
__global__ void rowcol_kernel(const float* __restrict__ pred, float* __restrict__ rs,
                              float* __restrict__ cs) {
    __shared__ float red[4];
    int blk = blockIdx.x, tid = threadIdx.x;
    float p = 0.f;
    if (blk < MNUM) {
        if (tid < MNUM) p = pred[blk * MNUM + tid];
    } else {
        int j = blk - MNUM;
        if (tid < MNUM) p = pred[tid * MNUM + j];
    }
    p = wave_reduce(p);
    if ((tid & 63) == 0) red[tid >> 6] = p;
    __syncthreads();
    if (tid == 0) {
        float s = red[0] + red[1] + red[2] + red[3];
        if (blk < MNUM) rs[blk] = s; else cs[blk - MNUM] = s;
    }
}

// K7: blocks 0..222: per-row ce/l2 plain stores. blocks 223..350: gsum dim
// reduction from gpart (plain stores).
__global__ void losses_kernel(const float* __restrict__ pred, const float* __restrict__ gt,
                              const float* __restrict__ rs, const float* __restrict__ cs,
                              const float* __restrict__ gpart, float* __restrict__ lce,
                              float* __restrict__ ll2, float* __restrict__ gsum, int nbuck) {
    __shared__ float redc[4], redl[4];
    int blk = blockIdx.x, tid = threadIdx.x;
    if (blk < MNUM) {
        float ce = 0.f, l2 = 0.f;
        if (tid < MNUM) {
            float p = pred[blk * MNUM + tid];
            ce = -gt[blk * MNUM + tid] * __log2f(p);
            l2 = p * (rs[blk] + cs[tid] - 2.0f * p);
        }
        ce = wave_reduce(ce);
        l2 = wave_reduce(l2);
        if ((tid & 63) == 0) { redc[tid >> 6] = ce; redl[tid >> 6] = l2; }
        __syncthreads();
        if (tid == 0) {
            lce[blk] = redc[0] + redc[1] + redc[2] + redc[3];
            ll2[blk] = redl[0] + redl[1] + redl[2] + redl[3];
        }
    } else {
        int dim = blk - MNUM;  // 0..127
        float s = 0.f;
        for (int b = tid; b < nbuck; b += 256) s += gpart[(size_t)b * 128 + dim];
        s = wave_reduce(s);
        if ((tid & 63) == 0) redc[tid >> 6] = s;
        __syncthreads();
        if (tid == 0) gsum[dim] = redc[0] + redc[1] + redc[2] + redc[3];
    }
}

// K8: single-block tail: all six outputs via plain stores.
__global__ void tail_kernel(const float* __restrict__ rs, const float* __restrict__ cs,
                            const float* __restrict__ lce, const float* __restrict__ ll2,
                            const float* __restrict__ psum, int npsum,
                            const float* __restrict__ ocpart, int nbuck,
                            const float* __restrict__ gsum, const float* __restrict__ fc3_w,
                            const float* __restrict__ fc3_b, const float* __restrict__ fl3_b,
                            float* __restrict__ out, int N, int padrows) {
    __shared__ float red[4];
    int tid = threadIdx.x;
    // sumone
    float v = 0.f;
    if (tid < MNUM) {
        float a = rs[tid] - 1.0f, b = cs[tid] - 1.0f;
        v = a * a + b * b;
    }
    v = wave_reduce(v);
    if ((tid & 63) == 0) red[tid >> 6] = v;
    __syncthreads();
    if (tid == 0) out[1] = red[0] + red[1] + red[2] + red[3];
    __syncthreads();
    // ce
    float ce = (tid < MNUM) ? lce[tid] : 0.f;
    ce = wave_reduce(ce);
    if ((tid & 63) == 0) red[tid >> 6] = ce;
    __syncthreads();
    if (tid == 0) out[3] = red[0] + red[1] + red[2] + red[3];
    __syncthreads();
    // loss2
    float l2 = (tid < MNUM) ? ll2[tid] : 0.f;
    l2 = wave_reduce(l2);
    if ((tid & 63) == 0) red[tid >> 6] = l2;
    __syncthreads();
    if (tid == 0) out[2] = red[0] + red[1] + red[2] + red[3];
    __syncthreads();
    // prob3_sum
    float ps = 0.f;
    for (int i = tid; i < npsum; i += 256) ps += psum[i];
    float ss = 0.f;
    for (int p = tid; p < PNUM; p += 256) ss += fsig_fast(fl3_b[p]);
    float comb = ps - (float)padrows * ss;
    comb = wave_reduce(comb);
    if ((tid & 63) == 0) red[tid >> 6] = comb;
    __syncthreads();
    if (tid == 0) out[5] = red[0] + red[1] + red[2] + red[3];
    __syncthreads();
    // out_cost
    float oc = 0.f;
    for (int b = tid; b < nbuck; b += 256) oc += ocpart[b];
    oc = wave_reduce(oc);
    if ((tid & 63) == 0) red[tid >> 6] = oc;
    __syncthreads();
    if (tid == 0) out[4] = red[0] + red[1] + red[2] + red[3];
    __syncthreads();
    // pred_obj
    float pv = 0.f;
    if (tid < 128) pv = gsum[tid] * (1.0f / (float)N) * fc3_w[tid];
    pv = wave_reduce(pv);
    if ((tid & 63) == 0) red[tid >> 6] = pv;
    __syncthreads();
    if (tid == 0) out[0] = red[0] + red[1] + fc3_b[0];
}

extern "C" void kernel_launch(void* const* d_in, const int* in_sizes, int n_in,
                              void* d_out, int out_size, void* d_ws, size_t ws_size,
                              hipStream_t stream) {
    const float* ntc   = (const float*)d_in[0];
    const float* norm  = (const float*)d_in[1];
    const float* sc    = (const float*)d_in[2];
    const float* gt    = (const float*)d_in[3];
    const float* fc_w  = (const float*)d_in[4];
    const float* fc_b  = (const float*)d_in[5];
    const float* w_nt  = (const float*)d_in[6];
    const float* w_rel = (const float*)d_in[7];
    const float* fc2_w = (const float*)d_in[8];
    const float* fc2_b = (const float*)d_in[9];
    const float* fc3_w = (const float*)d_in[10];
    const float* fc3_b = (const float*)d_in[11];
    const float* fl3_w = (const float*)d_in[12];
    const float* fl3_b = (const float*)d_in[13];
    const int* node_type = (const int*)d_in[14];
    const int* src   = (const int*)d_in[15];
    const int* dst   = (const int*)d_in[16];
    const int* etype = (const int*)d_in[17];
    int N = in_sizes[2];
    int E = in_sizes[1];
    int nb128 = (N + 127) / 128;             // 391
    int padN  = nb128 * 128;                 // 50048
    int nbuck = padN / BNODES;               // 782
    int npsum = nb128 * 2;                   // 782

    // ---- workspace layout (float offsets) ----
    // C:      0       .. 6144
    // wt:     6144    .. 71680   (1024*128 bf16)
    // biasws: 71680   .. 72704
    // gsum:   72704   .. 72832
    // rs:     72832   .. 73088
    // cs:     73088   .. 73344
    // cursor: 73344   .. 74128   (784 ints)
    // psum:   74128   .. 75152
    // lce:    75152   .. 75408
    // ll2:    75408   .. 75664
    // ocpart: 75664   .. 76688
    // gpart:  76688   .. 176784  (782*128)
    // pred:   176784  .. +N
    // hb:     +N      .. +N + padN*64
    // buck:   after   (nbuck*BCAP*2 floats)
    float* ws   = (float*)d_ws;
    float* C    = ws;
    unsigned short* wt = (unsigned short*)(ws + 6144);
    float* biasws = ws + 71680;
    float* gsum = ws + 72704;
    float* rs   = ws + 72832;
    float* cs   = ws + 73088;
    int*  cursor = (int*)(ws + 73344);
    float* psum = ws + 74128;
    float* lce  = ws + 75152;
    float* ll2  = ws + 75408;
    float* ocpart = ws + 75664;
    float* gpart  = ws + 76688;
    float* pred = ws + 176784;
    unsigned short* hb = (unsigned short*)(pred + N);
    uint2* buck = (uint2*)(hb + (size_t)padN * H);
    float* out  = (float*)d_out;

    hipMemsetAsync(d_out, 0, 6 * sizeof(float), stream);
    hipMemsetAsync(cursor, 0, 784 * sizeof(int), stream);
    hipMemsetAsync(hb + (size_t)N * H, 0, (size_t)(padN - N) * H * sizeof(unsigned short), stream);

    wt_kernel<<<1024, 128, 0, stream>>>(fl3_w, fl3_b, wt, biasws);
    precompute_CG<<<16, 128, 0, stream>>>(fc_w, fc_b, w_nt, w_rel, C);
    partition_kernel<<<(E + EPB - 1) / EPB, 1024, 0, stream>>>(src, dst, etype, norm,
                                                               node_type, cursor, buck, E);
    bucket_node<<<nbuck, 512, 0, stream>>>(buck, cursor, ntc, C, fc2_w, fc2_b,
                                           hb, pred, gpart, N);
    prob3_mfma<<<dim3(nb128, 2), 256, 0, stream>>>(hb, wt, biasws, psum, nb128);
    agg_outcost<<<nbuck, 256, 0, stream>>>(buck, cursor, pred, sc, ocpart, N);
    rowcol_kernel<<<2 * MNUM, 256, 0, stream>>>(pred, rs, cs);
    losses_kernel<<<MNUM + 128, 256, 0, stream>>>(pred, gt, rs, cs, gpart, lce, ll2, gsum, nbuck);
    tail_kernel<<<1, 256, 0, stream>>>(rs, cs, lce, ll2, psum, npsum, ocpart, nbuck,
                                       gsum, fc3_w, fc3_b, fl3_b, out, N, padN - N);
}